// Round 1
// 1549.266 us; speedup vs baseline: 1.1978x; 1.1978x over previous
//
#include <hip/hip_runtime.h>
#include <hip/hip_bf16.h>

typedef unsigned short u16;
typedef unsigned int u32;
typedef __bf16 bf16x8 __attribute__((ext_vector_type(8)));
typedef float f32x4 __attribute__((ext_vector_type(4)));

// output element offsets (f32 elements)
#define OUT_POOLED 0
#define OUT_MEM    6291456
#define OUT_STATE  56623104
#define OUT_HOLD   65011712
#define OUT_ROUTE  65208320

__device__ __forceinline__ float b2f(u16 u){ u32 v=((u32)u)<<16; float f; __builtin_memcpy(&f,&v,4); return f; }
__device__ __forceinline__ u16 f2b(float f){ __hip_bfloat16 h=__float2bfloat16(f); u16 r; __builtin_memcpy(&r,&h,2); return r; }
__device__ __forceinline__ float sigf(float x){ return __builtin_amdgcn_rcpf(1.0f+__builtin_amdgcn_exp2f(-1.4426950408889634f*x)); }
__device__ __forceinline__ float tanh_(float x){ return 1.0f-2.0f*__builtin_amdgcn_rcpf(1.0f+__builtin_amdgcn_exp2f(2.8853900817779268f*x)); }
__device__ __forceinline__ float geluf(float x){
  float z = 0.7071067811865476f*x;
  float az = __builtin_fabsf(z);
  float t = __builtin_amdgcn_rcpf(1.0f+0.3275911f*az);
  float p = t*(0.254829592f+t*(-0.284496736f+t*(1.421413741f+t*(-1.453152027f+t*1.061405429f))));
  float e = __builtin_amdgcn_exp2f(-1.4426950408889634f*az*az);
  float er = 1.0f-p*e;
  er = (z<0.0f)? -er : er;
  return 0.5f*x*(1.0f+er);
}

// ---------------- prep: wcat pack (bf16), bcat, b_comb ----------------
// bcomb re-decomposed: one WAVE per output row (was one thread -> 3 CUs latency-bound)
__global__ void k_prep(const float* __restrict__ Ws, const float* __restrict__ bs,
                       const float* __restrict__ bm, const float* __restrict__ Wm,
                       const float* __restrict__ Wh1, const float* __restrict__ bh1,
                       const float* __restrict__ Wt1, const float* __restrict__ bt1,
                       const float* __restrict__ Wv1, const float* __restrict__ bv1,
                       u16* __restrict__ wcat, float* __restrict__ bcat, float* __restrict__ bcomb)
{
  __shared__ float bmS[768];
  int tid = threadIdx.x;
  for(int i=tid;i<768;i+=256) bmS[i]=bm[i];
  __syncthreads();
  // bcomb: grid 192 x 4 waves, one wave per d
  {
    int w = tid>>6, lane = tid&63;
    int d = blockIdx.x*4 + w;
    float acc=0.f;
    for(int e=0;e<8;e++){
      const float* row = Ws + (size_t)d*6144 + e*768;
      #pragma unroll
      for(int it=0; it<3; it++){
        int c = it*256 + lane*4;
        float4 u = *reinterpret_cast<const float4*>(row + c);
        acc += u.x*bmS[c]+u.y*bmS[c+1]+u.z*bmS[c+2]+u.w*bmS[c+3];
      }
    }
    #pragma unroll
    for(int o=32;o>0;o>>=1) acc += __shfl_down(acc,o);
    if(lane==0) bcomb[d]=bs[d]+acc;
  }
  // bcat (960) + wcat (122880)
  for(int idx = blockIdx.x*256+tid; idx<123840; idx += gridDim.x*256){
    if(idx<960){
      int n=idx;
      float v;
      if(n<768) v=bm[n];
      else { int j=n-768; v = (j<64)? bh1[j] : (j<128)? bt1[j-64] : bv1[j-128]; }
      bcat[n]=v;
    } else {
      int c=idx-960; int n=c>>7, k=c&127;
      float v;
      if(n<768) v=Wm[n*128+k];
      else if(n<832) v=Wh1[(n-768)*128+k];
      else if(n<896) v=Wt1[(n-832)*128+k];
      else v=Wv1[(n-896)*128+k];
      wcat[c]=f2b(v);
    }
  }
}

// ---------------- Wcomb[d][e*128+s] = sum_d2 Ws[d][e*768+d2]*Wm[d2][s] (bf16 out) ----------------
__global__ __launch_bounds__(256) void k_wcomb(const float* __restrict__ Ws, const float* __restrict__ Wm,
                                               u16* __restrict__ wcomb)
{
  __shared__ float WmS[96][128];
  __shared__ float WsS[64][96];
  int tid=threadIdx.x;
  int e = blockIdx.x/12, dt = blockIdx.x%12;
  int d0 = dt*64;
  int s = tid&127, dh = tid>>7;
  float acc[32];
  #pragma unroll
  for(int i=0;i<32;i++) acc[i]=0.f;
  for(int c=0;c<8;c++){
    int c0=c*96;
    __syncthreads();
    for(int it=0; it<12; it++){
      int v=it*256+tid; int r=v>>5, c4=(v&31)*4;
      *reinterpret_cast<float4*>(&WmS[r][c4]) = *reinterpret_cast<const float4*>(Wm + (c0+r)*128 + c4);
    }
    for(int it=0; it<6; it++){
      int v=it*256+tid; int dl=v/24, c4=(v%24)*4;
      *reinterpret_cast<float4*>(&WsS[dl][c4]) = *reinterpret_cast<const float4*>(Ws + (d0+dl)*6144 + e*768 + c0 + c4);
    }
    __syncthreads();
    for(int d2=0; d2<96; d2++){
      float wm = WmS[d2][s];
      #pragma unroll
      for(int ds=0; ds<32; ds++) acc[ds] += WsS[dh*32+ds][d2]*wm;
    }
  }
  for(int ds=0; ds<32; ds++){
    int d = d0 + dh*32 + ds;
    wcomb[d*1024 + e*128 + s] = f2b(acc[ds]);
  }
}

// ---------------- routing softmax + q = W_ih@(Wi@h + bi) ----------------
__global__ __launch_bounds__(256) void k_route(const float* __restrict__ hseq, const float* __restrict__ ek,
                                               const float* __restrict__ Wi, const float* __restrict__ bi,
                                               const float* __restrict__ Wih,
                                               float* __restrict__ qws, float* __restrict__ out)
{
  __shared__ float hrow[8][768];
  __shared__ float projS[8][128];
  __shared__ float lgs[8][8];
  int tid=threadIdx.x;
  int row0 = blockIdx.x*8;
  for(int it=0; it<6; it++){
    int v=it*256+tid; int r=v/192, c4=(v%192)*4;
    *reinterpret_cast<float4*>(&hrow[r][c4]) = *reinterpret_cast<const float4*>(hseq + (row0+r)*768 + c4);
  }
  __syncthreads();
  if(tid<64){
    int r=tid>>3, e=tid&7;
    float acc=0.f;
    for(int k0=0;k0<768;k0+=4){
      float4 u=*reinterpret_cast<const float4*>(ek + e*768 + k0);
      const float* h=&hrow[r][k0];
      acc += u.x*h[0]+u.y*h[1]+u.z*h[2]+u.w*h[3];
    }
    lgs[r][e] = acc * (1.0f/27.712812921102035f);
  }
  __syncthreads();
  if(tid<8){
    int r=tid;
    float l[8], m=-1e30f;
    #pragma unroll
    for(int e=0;e<8;e++){ l[e]=lgs[r][e]; m=fmaxf(m,l[e]); }
    float s=0.f;
    #pragma unroll
    for(int e=0;e<8;e++){ l[e]=__builtin_amdgcn_exp2f(1.4426950408889634f*(l[e]-m)); s+=l[e]; }
    float inv=__builtin_amdgcn_rcpf(s);
    #pragma unroll
    for(int e=0;e<8;e++){
      out[OUT_ROUTE + (row0+r)*8 + e] = l[e]*inv;
    }
  }
  // proj = Wi@h + bi
  {
    int j=tid&127, rh=tid>>7;
    float facc[4];
    float bj=bi[j];
    #pragma unroll
    for(int rr=0;rr<4;rr++) facc[rr]=bj;
    for(int k0=0;k0<768;k0+=4){
      float4 u=*reinterpret_cast<const float4*>(Wi + j*768 + k0);
      #pragma unroll
      for(int rr=0;rr<4;rr++){
        const float* h=&hrow[rh*4+rr][k0];
        facc[rr] += u.x*h[0]+u.y*h[1]+u.z*h[2]+u.w*h[3];
      }
    }
    #pragma unroll
    for(int rr=0;rr<4;rr++) projS[rh*4+rr][j]=facc[rr];
  }
  __syncthreads();
  // q = W_ih @ proj
  for(int p=0;p<12;p++){
    int task=p*256+tid;
    int r=task/384, jq=task%384;
    float acc=0.f;
    for(int k0=0;k0<128;k0+=4){
      float4 u=*reinterpret_cast<const float4*>(Wih + jq*128 + k0);
      const float* pr=&projS[r][k0];
      acc += u.x*pr[0]+u.y*pr[1]+u.z*pr[2]+u.w*pr[3];
    }
    qws[(row0+r)*384 + jq]=acc;
  }
}

// ---------------- gpre packed layout: [b][t][ch][half][12] u16 ----------------
// per (b,t): ch in [0,128), half in {0,1} (e range half*4..half*4+3)
// element (i,g) at offset ch*24 + half*12 + i*3 + g, value = w[b,t,half*4+i]*q[g*128+ch] + bias(g*128+ch)
__global__ __launch_bounds__(256) void k_gpre(const float* __restrict__ qws, const float* __restrict__ out,
                                              const float* __restrict__ bih, const float* __restrict__ bhh,
                                              u16* __restrict__ gpre)
{
  __shared__ float wS[8];
  __shared__ float qS[384];
  __shared__ float bS[384];
  int tid=threadIdx.x;
  int bt=blockIdx.x;
  if(tid<8) wS[tid]=out[OUT_ROUTE + bt*8 + tid];
  if(tid>=128 && tid<224){ int j=tid-128; *reinterpret_cast<float4*>(&qS[j*4]) = *reinterpret_cast<const float4*>(qws + bt*384 + j*4); }
  if(tid<96){
    int c4=tid*4;
    float4 u=*reinterpret_cast<const float4*>(bih+c4);
    if(c4<256){
      float4 v=*reinterpret_cast<const float4*>(bhh+c4);
      u.x+=v.x; u.y+=v.y; u.z+=v.z; u.w+=v.w;
    }
    *reinterpret_cast<float4*>(&bS[c4])=u;
  }
  __syncthreads();
  int ch=tid>>1, e0=(tid&1)*4;
  u16 ov[12];
  #pragma unroll
  for(int i=0;i<4;i++){
    float wv=wS[e0+i];
    #pragma unroll
    for(int g=0;g<3;g++){
      int col=g*128+ch;
      ov[i*3+g]=f2b(wv*qS[col]+bS[col]);
    }
  }
  u16* dst = gpre + (size_t)bt*3072 + tid*12;   // tid*12 == ch*24 + half*12
  uint2 o[3];
  __builtin_memcpy(o,ov,24);
  *reinterpret_cast<uint2*>(dst)  =o[0];
  *reinterpret_cast<uint2*>(dst+4)=o[1];
  *reinterpret_cast<uint2*>(dst+8)=o[2];
}

// ---------------- sequential GRU scan ----------------
// KEY CHANGE vs prior version: __syncthreads() forced s_waitcnt vmcnt(0) each step,
// draining the HBM gpre prefetch (~900cy) into every one of the 1024 steps.
// Now: lgkmcnt-only asm barrier (LDS h-exchange is the only cross-wave dep),
// distance-4 register prefetch of packed gpre (3 x uint2 per lane per step).
// Shadow stores legally stay in flight across the barrier.
#define SCAN_SYNC asm volatile("s_waitcnt lgkmcnt(0)\n\ts_barrier" ::: "memory")

#define SCAN_STEP(BUF,NXT,P,DOLOAD)                                                         \
  {                                                                                         \
    bf16x8 af[4];                                                                           \
    _Pragma("unroll")                                                                       \
    for(int kt=0;kt<4;kt++)                                                                 \
      af[kt]=__builtin_bit_cast(bf16x8, *reinterpret_cast<const uint4*>(&hbf[BUF][il][kt*32+q4*8])); \
    u16 cw[12];                                                                             \
    __builtin_memcpy(cw+0,&ga[P],8);                                                        \
    __builtin_memcpy(cw+4,&gb[P],8);                                                        \
    __builtin_memcpy(cw+8,&gc[P],8);                                                        \
    if(DOLOAD){                                                                             \
      ga[P]=*reinterpret_cast<const uint2*>(gp);                                            \
      gb[P]=*reinterpret_cast<const uint2*>(gp+4);                                          \
      gc[P]=*reinterpret_cast<const uint2*>(gp+8);                                          \
      gp+=3072;                                                                             \
    }                                                                                       \
    f32x4 acc0={0.f,0.f,0.f,0.f}, acc1={0.f,0.f,0.f,0.f}, acc2={0.f,0.f,0.f,0.f};           \
    _Pragma("unroll")                                                                       \
    for(int kt=0;kt<4;kt++){                                                                \
      acc0=__builtin_amdgcn_mfma_f32_16x16x32_bf16(af[kt],bfr0[kt],acc0,0,0,0);             \
      acc1=__builtin_amdgcn_mfma_f32_16x16x32_bf16(af[kt],bfr1[kt],acc1,0,0,0);             \
      acc2=__builtin_amdgcn_mfma_f32_16x16x32_bf16(af[kt],bfr2[kt],acc2,0,0,0);             \
    }                                                                                       \
    _Pragma("unroll")                                                                       \
    for(int i=0;i<4;i++){                                                                   \
      float r=sigf(acc0[i]+b2f(cw[i*3+0]));                                                 \
      float z=sigf(acc1[i]+b2f(cw[i*3+1]));                                                 \
      float n=tanh_(b2f(cw[i*3+2])+r*(acc2[i]+bhhn));                                       \
      float hn=n+z*(hp[i]-n);                                                               \
      hp[i]=hn;                                                                             \
      u16 hb=f2b(hn);                                                                       \
      hbf[NXT][q4*4+i][ch]=hb;                                                              \
      sbase[i*128]=hb;                                                                      \
    }                                                                                       \
    sbase += 1024;                                                                          \
    SCAN_SYNC;                                                                              \
  }

__global__ __launch_bounds__(512,1) void k_scan(const float* __restrict__ Whh, const float* __restrict__ bhh,
                                                const float* __restrict__ state0,
                                                const u16* __restrict__ gpre, u16* __restrict__ shadow)
{
  __shared__ u16 hbf[2][16][136];
  int tid=threadIdx.x;
  int w=tid>>6, L=tid&63, q4=L>>4, il=L&15;
  int b0=blockIdx.x*2;
  int ch=w*16+il;
  int bl=q4>>1, half=q4&1, e0=half*4;
  // persistent B-fragments of W_hh (N=384 gate cols x K=128), cvt f32->bf16
  bf16x8 bfr0[4], bfr1[4], bfr2[4];
  #pragma unroll
  for(int kt=0; kt<4; kt++){
    u16 t0[8],t1[8],t2[8];
    #pragma unroll
    for(int j=0;j<8;j++){
      t0[j]=f2b(Whh[(0*128+ch)*128 + kt*32 + q4*8 + j]);
      t1[j]=f2b(Whh[(1*128+ch)*128 + kt*32 + q4*8 + j]);
      t2[j]=f2b(Whh[(2*128+ch)*128 + kt*32 + q4*8 + j]);
    }
    __builtin_memcpy(&bfr0[kt],t0,16);
    __builtin_memcpy(&bfr1[kt],t1,16);
    __builtin_memcpy(&bfr2[kt],t2,16);
  }
  float bhhn = bhh[256+ch];
  // register-carried h (f32) for this lane's 4 (row,ch) cells
  float hp[4];
  #pragma unroll
  for(int i=0;i<4;i++) hp[i]=state0[(e0+i)*128+ch];
  // init bf16 h tile
  for(int idx=tid; idx<2048; idx+=512){
    int m=idx>>7, c=idx&127;
    hbf[0][m][c]=f2b(state0[(m&7)*128+c]);
  }
  // per-lane streaming pointers (packed gpre layout)
  const u16* gp = gpre + (size_t)(b0+bl)*1024*3072 + ch*24 + half*12;
  u16* sbase = shadow + ((size_t)(b0+bl)*8192 + e0)*128 + ch;
  // distance-4 prefetch buffers (statically indexed)
  uint2 ga[4], gb[4], gc[4];
  #pragma unroll
  for(int p=0;p<4;p++){
    ga[p]=*reinterpret_cast<const uint2*>(gp);
    gb[p]=*reinterpret_cast<const uint2*>(gp+4);
    gc[p]=*reinterpret_cast<const uint2*>(gp+8);
    gp+=3072;
  }
  SCAN_SYNC;
  #pragma unroll 1
  for(int t2=0;t2<255;t2++){
    SCAN_STEP(0,1,0,1)
    SCAN_STEP(1,0,1,1)
    SCAN_STEP(0,1,2,1)
    SCAN_STEP(1,0,3,1)
  }
  // epilogue: last 4 steps, no prefetch (no OOB reads)
  SCAN_STEP(0,1,0,0)
  SCAN_STEP(1,0,1,0)
  SCAN_STEP(0,1,2,0)
  SCAN_STEP(1,0,3,0)
}

// ---------------- expand bf16 shadow -> f32 OUT_STATE ----------------
__global__ __launch_bounds__(256) void k_expand(const u16* __restrict__ sh, float* __restrict__ o)
{
  int idx=(blockIdx.x*256+threadIdx.x)*4;
  uint2 u=*reinterpret_cast<const uint2*>(sh+idx);
  float4 f;
  f.x=b2f((u16)(u.x&0xffffu)); f.y=b2f((u16)(u.x>>16));
  f.z=b2f((u16)(u.y&0xffffu)); f.w=b2f((u16)(u.y>>16));
  *reinterpret_cast<float4*>(o+idx)=f;
}

// ---------------- memory_stack + head hidden (GEMM [65536x128]@[128x960]) ----------------
__global__ __launch_bounds__(256) void k_mem(const u16* __restrict__ state, const u16* __restrict__ wcat,
                                             const float* __restrict__ bcat,
                                             float* __restrict__ memout, u16* __restrict__ hdn)
{
  __shared__ u16 As[128][136];
  __shared__ u16 Bs[96][136];
  int tid=threadIdx.x;
  int bx=blockIdx.x, ny=blockIdx.y;
  for(int it=0;it<8;it++){
    int v=it*256+tid; int r=v>>4, c8=(v&15)*8;
    *reinterpret_cast<uint4*>(&As[r][c8]) = *reinterpret_cast<const uint4*>(state + (bx*128+r)*128 + c8);
  }
  for(int it=0;it<6;it++){
    int v=it*256+tid; int r=v>>4, c8=(v&15)*8;
    *reinterpret_cast<uint4*>(&Bs[r][c8]) = *reinterpret_cast<const uint4*>(wcat + (ny*96+r)*128 + c8);
  }
  __syncthreads();
  int w=tid>>6, L=tid&63, q4=L>>4, il=L&15;
  int msub=w*32;
  bf16x8 af[2][4];
  #pragma unroll
  for(int tm=0;tm<2;tm++)
    #pragma unroll
    for(int kt=0;kt<4;kt++)
      af[tm][kt]=__builtin_bit_cast(bf16x8,*reinterpret_cast<const uint4*>(&As[msub+tm*16+il][kt*32+q4*8]));
  const f32x4 fz = {0.f,0.f,0.f,0.f};
  f32x4 acc[2][6];
  #pragma unroll
  for(int tm=0;tm<2;tm++){
    #pragma unroll
    for(int tn=0;tn<6;tn++) acc[tm][tn]=fz;
  }
  #pragma unroll
  for(int tn=0;tn<6;tn++){
    bf16x8 bf[4];
    #pragma unroll
    for(int kt=0;kt<4;kt++)
      bf[kt]=__builtin_bit_cast(bf16x8,*reinterpret_cast<const uint4*>(&Bs[tn*16+il][kt*32+q4*8]));
    #pragma unroll
    for(int tm=0;tm<2;tm++){
      #pragma unroll
      for(int kt=0;kt<4;kt++)
        acc[tm][tn]=__builtin_amdgcn_mfma_f32_16x16x32_bf16(af[tm][kt],bf[kt],acc[tm][tn],0,0,0);
    }
  }
  #pragma unroll
  for(int tm=0;tm<2;tm++){
    #pragma unroll
    for(int tn=0;tn<6;tn++){
      int col=ny*96+tn*16+il;
      float bias=bcat[col];
      #pragma unroll
      for(int i=0;i<4;i++){
        int row=bx*128+msub+tm*16+q4*4+i;
        float val=acc[tm][tn][i]+bias;
        if(ny<8) memout[row*768+col]=val;
        else hdn[row*192+(col-768)]=f2b(geluf(val));
      }
    }
  }
}

// ---------------- pooled = state_flat[8192x1024] @ Wcomb.T + b_comb ----------------
__global__ __launch_bounds__(256) void k_pool(const u16* __restrict__ state, const u16* __restrict__ wcomb,
                                              const float* __restrict__ bcomb, float* __restrict__ pooled)
{
  __shared__ u16 As[128][136];
  __shared__ u16 Bs[96][136];
  int tid=threadIdx.x;
  int bx=blockIdx.x, ny=blockIdx.y;
  int w=tid>>6, L=tid&63, q4=L>>4, il=L&15;
  int msub=w*32;
  const f32x4 fz = {0.f,0.f,0.f,0.f};
  f32x4 acc[2][6];
  #pragma unroll
  for(int tm=0;tm<2;tm++){
    #pragma unroll
    for(int tn=0;tn<6;tn++) acc[tm][tn]=fz;
  }
  for(int kc=0;kc<8;kc++){
    __syncthreads();
    for(int it=0;it<8;it++){
      int v=it*256+tid; int r=v>>4, c8=(v&15)*8;
      *reinterpret_cast<uint4*>(&As[r][c8]) = *reinterpret_cast<const uint4*>(state + (bx*128+r)*1024 + kc*128 + c8);
    }
    for(int it=0;it<6;it++){
      int v=it*256+tid; int r=v>>4, c8=(v&15)*8;
      *reinterpret_cast<uint4*>(&Bs[r][c8]) = *reinterpret_cast<const uint4*>(wcomb + (ny*96+r)*1024 + kc*128 + c8);
    }
    __syncthreads();
    bf16x8 af[2][4];
    #pragma unroll
    for(int tm=0;tm<2;tm++)
      #pragma unroll
      for(int kt=0;kt<4;kt++)
        af[tm][kt]=__builtin_bit_cast(bf16x8,*reinterpret_cast<const uint4*>(&As[msub+tm*16+il][kt*32+q4*8]));
    #pragma unroll
    for(int tn=0;tn<6;tn++){
      bf16x8 bf[4];
      #pragma unroll
      for(int kt=0;kt<4;kt++)
        bf[kt]=__builtin_bit_cast(bf16x8,*reinterpret_cast<const uint4*>(&Bs[tn*16+il][kt*32+q4*8]));
      #pragma unroll
      for(int tm=0;tm<2;tm++){
        #pragma unroll
        for(int kt=0;kt<4;kt++)
          acc[tm][tn]=__builtin_amdgcn_mfma_f32_16x16x32_bf16(af[tm][kt],bf[kt],acc[tm][tn],0,0,0);
      }
    }
  }
  #pragma unroll
  for(int tm=0;tm<2;tm++){
    #pragma unroll
    for(int tn=0;tn<6;tn++){
      int col=ny*96+tn*16+il;
      float bias=bcomb[col];
      #pragma unroll
      for(int i=0;i<4;i++){
        int row=bx*128+msub+tm*16+q4*4+i;
        pooled[row*768+col]=acc[tm][tn][i]+bias;
      }
    }
  }
}

// ---------------- head second layer ----------------
__global__ __launch_bounds__(256) void k_heads(const u16* __restrict__ hdn,
                                               const float* __restrict__ Wh2, const float* __restrict__ bh2,
                                               const float* __restrict__ Wt2, const float* __restrict__ bt2,
                                               const float* __restrict__ Wv2, const float* __restrict__ bv2,
                                               float* __restrict__ out)
{
  int oid=blockIdx.x*256+threadIdx.x;
  int row=oid&65535, head=oid>>16;
  const float* w2 = (head==0)?Wh2:(head==1)?Wt2:Wv2;
  float b2 = ((head==0)?bh2:(head==1)?bt2:bv2)[0];
  float acc=0.f;
  const u16* src = hdn + row*192 + head*64;
  for(int j0=0;j0<64;j0+=8){
    uint4 hu=*reinterpret_cast<const uint4*>(src+j0);
    u16 hs[8]; __builtin_memcpy(hs,&hu,16);
    #pragma unroll
    for(int j=0;j<8;j++) acc+=b2f(hs[j])*w2[j0+j];
  }
  out[OUT_HOLD + head*65536 + row]=acc+b2;
}

extern "C" void kernel_launch(void* const* d_in, const int* in_sizes, int n_in,
                              void* d_out, int out_size, void* d_ws, size_t ws_size,
                              hipStream_t stream)
{
  const float* hseq=(const float*)d_in[0];
  const float* ek  =(const float*)d_in[1];
  const float* st0 =(const float*)d_in[2];
  const float* Wi  =(const float*)d_in[3];
  const float* bi  =(const float*)d_in[4];
  const float* Wih =(const float*)d_in[5];
  const float* Whh =(const float*)d_in[6];
  const float* bih =(const float*)d_in[7];
  const float* bhh =(const float*)d_in[8];
  const float* Wm  =(const float*)d_in[9];
  const float* bm  =(const float*)d_in[10];
  const float* Ws  =(const float*)d_in[11];
  const float* bs  =(const float*)d_in[12];
  const float* Wh1 =(const float*)d_in[13];
  const float* bh1 =(const float*)d_in[14];
  const float* Wh2 =(const float*)d_in[15];
  const float* bh2 =(const float*)d_in[16];
  const float* Wt1 =(const float*)d_in[17];
  const float* bt1 =(const float*)d_in[18];
  const float* Wt2 =(const float*)d_in[19];
  const float* bt2 =(const float*)d_in[20];
  const float* Wv1 =(const float*)d_in[21];
  const float* bv1 =(const float*)d_in[22];
  const float* Wv2 =(const float*)d_in[23];
  const float* bv2 =(const float*)d_in[24];
  float* out=(float*)d_out;
  char* ws=(char*)d_ws;
  float* qws  =(float*)ws;                 // 8192*384*4          = 12,582,912
  u16*  gpre  =(u16*)(ws+12582912);        // 65536*384*2 + 16K   = 50,348,032  -> 62,930,944
  u16*  wcomb =(u16*)(ws+62930944);        // 768*1024*2          =  1,572,864  -> 64,503,808
  float* bcomb=(float*)(ws+64503808);      // 768*4               =      3,072  -> 64,506,880
  u16*  wcat  =(u16*)(ws+64506880);        // 960*128*2           =    245,760  -> 64,752,640
  float* bcat =(float*)(ws+64752640);      // 960*4               =      3,840  -> 64,756,480
  u16*  hdn   =(u16*)(ws+64756480);        // 65536*192*2         = 25,165,824  -> 89,922,304
  u16*  shadow=(u16*)(ws+89922304);        // 65536*128*2         = 16,777,216  -> 106,699,520

  hipLaunchKernelGGL(k_prep, dim3(192), dim3(256), 0, stream,
                     Ws,bs,bm,Wm,Wh1,bh1,Wt1,bt1,Wv1,bv1,wcat,bcat,bcomb);
  hipLaunchKernelGGL(k_wcomb, dim3(96), dim3(256), 0, stream, Ws,Wm,wcomb);
  hipLaunchKernelGGL(k_route, dim3(1024), dim3(256), 0, stream, hseq,ek,Wi,bi,Wih,qws,out);
  hipLaunchKernelGGL(k_gpre, dim3(8192), dim3(256), 0, stream, qws,out,bih,bhh,gpre);
  hipLaunchKernelGGL(k_scan, dim3(4), dim3(512), 0, stream, Whh,bhh,st0,gpre,shadow);
  hipLaunchKernelGGL(k_expand, dim3(8192), dim3(256), 0, stream, shadow,out+OUT_STATE);
  hipLaunchKernelGGL(k_mem, dim3(512,10), dim3(256), 0, stream, shadow,wcat,bcat,out+OUT_MEM,hdn);
  hipLaunchKernelGGL(k_pool, dim3(64,8), dim3(256), 0, stream, shadow,wcomb,bcomb,out+OUT_POOLED);
  hipLaunchKernelGGL(k_heads, dim3(768), dim3(256), 0, stream, hdn,Wh2,bh2,Wt2,bt2,Wv2,bv2,out);
}

// Round 2
// 1280.258 us; speedup vs baseline: 1.4494x; 1.2101x over previous
//
#include <hip/hip_runtime.h>
#include <hip/hip_bf16.h>

typedef unsigned short u16;
typedef unsigned int u32;
typedef __bf16 bf16x8 __attribute__((ext_vector_type(8)));
typedef float f32x4 __attribute__((ext_vector_type(4)));

// output element offsets (f32 elements)
#define OUT_POOLED 0
#define OUT_MEM    6291456
#define OUT_STATE  56623104
#define OUT_HOLD   65011712
#define OUT_ROUTE  65208320

__device__ __forceinline__ float b2f(u16 u){ u32 v=((u32)u)<<16; float f; __builtin_memcpy(&f,&v,4); return f; }
__device__ __forceinline__ u16 f2b(float f){ __hip_bfloat16 h=__float2bfloat16(f); u16 r; __builtin_memcpy(&r,&h,2); return r; }
__device__ __forceinline__ float sigf(float x){ return __builtin_amdgcn_rcpf(1.0f+__builtin_amdgcn_exp2f(-1.4426950408889634f*x)); }
__device__ __forceinline__ float tanh_(float x){ return 1.0f-2.0f*__builtin_amdgcn_rcpf(1.0f+__builtin_amdgcn_exp2f(2.8853900817779268f*x)); }
__device__ __forceinline__ float geluf(float x){
  float z = 0.7071067811865476f*x;
  float az = __builtin_fabsf(z);
  float t = __builtin_amdgcn_rcpf(1.0f+0.3275911f*az);
  float p = t*(0.254829592f+t*(-0.284496736f+t*(1.421413741f+t*(-1.453152027f+t*1.061405429f))));
  float e = __builtin_amdgcn_exp2f(-1.4426950408889634f*az*az);
  float er = 1.0f-p*e;
  er = (z<0.0f)? -er : er;
  return 0.5f*x*(1.0f+er);
}

// ---------------- prep: wcat pack (bf16), bcat, b_comb ----------------
__global__ void k_prep(const float* __restrict__ Ws, const float* __restrict__ bs,
                       const float* __restrict__ bm, const float* __restrict__ Wm,
                       const float* __restrict__ Wh1, const float* __restrict__ bh1,
                       const float* __restrict__ Wt1, const float* __restrict__ bt1,
                       const float* __restrict__ Wv1, const float* __restrict__ bv1,
                       u16* __restrict__ wcat, float* __restrict__ bcat, float* __restrict__ bcomb)
{
  __shared__ float bmS[768];
  int tid = threadIdx.x;
  for(int i=tid;i<768;i+=256) bmS[i]=bm[i];
  __syncthreads();
  // bcomb: grid 192 x 4 waves, one wave per d
  {
    int w = tid>>6, lane = tid&63;
    int d = blockIdx.x*4 + w;
    float acc=0.f;
    for(int e=0;e<8;e++){
      const float* row = Ws + (size_t)d*6144 + e*768;
      #pragma unroll
      for(int it=0; it<3; it++){
        int c = it*256 + lane*4;
        float4 u = *reinterpret_cast<const float4*>(row + c);
        acc += u.x*bmS[c]+u.y*bmS[c+1]+u.z*bmS[c+2]+u.w*bmS[c+3];
      }
    }
    #pragma unroll
    for(int o=32;o>0;o>>=1) acc += __shfl_down(acc,o);
    if(lane==0) bcomb[d]=bs[d]+acc;
  }
  // bcat (960) + wcat (122880)
  for(int idx = blockIdx.x*256+tid; idx<123840; idx += gridDim.x*256){
    if(idx<960){
      int n=idx;
      float v;
      if(n<768) v=bm[n];
      else { int j=n-768; v = (j<64)? bh1[j] : (j<128)? bt1[j-64] : bv1[j-128]; }
      bcat[n]=v;
    } else {
      int c=idx-960; int n=c>>7, k=c&127;
      float v;
      if(n<768) v=Wm[n*128+k];
      else if(n<832) v=Wh1[(n-768)*128+k];
      else if(n<896) v=Wt1[(n-832)*128+k];
      else v=Wv1[(n-896)*128+k];
      wcat[c]=f2b(v);
    }
  }
}

// ---------------- Wcomb[d][e*128+s] = sum_d2 Ws[d][e*768+d2]*Wm[d2][s] (bf16 out) ----------------
__global__ __launch_bounds__(256) void k_wcomb(const float* __restrict__ Ws, const float* __restrict__ Wm,
                                               u16* __restrict__ wcomb)
{
  __shared__ float WmS[96][128];
  __shared__ float WsS[64][96];
  int tid=threadIdx.x;
  int e = blockIdx.x/12, dt = blockIdx.x%12;
  int d0 = dt*64;
  int s = tid&127, dh = tid>>7;
  float acc[32];
  #pragma unroll
  for(int i=0;i<32;i++) acc[i]=0.f;
  for(int c=0;c<8;c++){
    int c0=c*96;
    __syncthreads();
    for(int it=0; it<12; it++){
      int v=it*256+tid; int r=v>>5, c4=(v&31)*4;
      *reinterpret_cast<float4*>(&WmS[r][c4]) = *reinterpret_cast<const float4*>(Wm + (c0+r)*128 + c4);
    }
    for(int it=0; it<6; it++){
      int v=it*256+tid; int dl=v/24, c4=(v%24)*4;
      *reinterpret_cast<float4*>(&WsS[dl][c4]) = *reinterpret_cast<const float4*>(Ws + (d0+dl)*6144 + e*768 + c0 + c4);
    }
    __syncthreads();
    for(int d2=0; d2<96; d2++){
      float wm = WmS[d2][s];
      #pragma unroll
      for(int ds=0; ds<32; ds++) acc[ds] += WsS[dh*32+ds][d2]*wm;
    }
  }
  for(int ds=0; ds<32; ds++){
    int d = d0 + dh*32 + ds;
    wcomb[d*1024 + e*128 + s] = f2b(acc[ds]);
  }
}

// ---------------- routing softmax + q = W_ih@(Wi@h + bi) ----------------
__global__ __launch_bounds__(256) void k_route(const float* __restrict__ hseq, const float* __restrict__ ek,
                                               const float* __restrict__ Wi, const float* __restrict__ bi,
                                               const float* __restrict__ Wih,
                                               float* __restrict__ qws, float* __restrict__ out)
{
  __shared__ float hrow[8][768];
  __shared__ float projS[8][128];
  __shared__ float lgs[8][8];
  int tid=threadIdx.x;
  int row0 = blockIdx.x*8;
  for(int it=0; it<6; it++){
    int v=it*256+tid; int r=v/192, c4=(v%192)*4;
    *reinterpret_cast<float4*>(&hrow[r][c4]) = *reinterpret_cast<const float4*>(hseq + (row0+r)*768 + c4);
  }
  __syncthreads();
  if(tid<64){
    int r=tid>>3, e=tid&7;
    float acc=0.f;
    for(int k0=0;k0<768;k0+=4){
      float4 u=*reinterpret_cast<const float4*>(ek + e*768 + k0);
      const float* h=&hrow[r][k0];
      acc += u.x*h[0]+u.y*h[1]+u.z*h[2]+u.w*h[3];
    }
    lgs[r][e] = acc * (1.0f/27.712812921102035f);
  }
  __syncthreads();
  if(tid<8){
    int r=tid;
    float l[8], m=-1e30f;
    #pragma unroll
    for(int e=0;e<8;e++){ l[e]=lgs[r][e]; m=fmaxf(m,l[e]); }
    float s=0.f;
    #pragma unroll
    for(int e=0;e<8;e++){ l[e]=__builtin_amdgcn_exp2f(1.4426950408889634f*(l[e]-m)); s+=l[e]; }
    float inv=__builtin_amdgcn_rcpf(s);
    #pragma unroll
    for(int e=0;e<8;e++){
      out[OUT_ROUTE + (row0+r)*8 + e] = l[e]*inv;
    }
  }
  // proj = Wi@h + bi
  {
    int j=tid&127, rh=tid>>7;
    float facc[4];
    float bj=bi[j];
    #pragma unroll
    for(int rr=0;rr<4;rr++) facc[rr]=bj;
    for(int k0=0;k0<768;k0+=4){
      float4 u=*reinterpret_cast<const float4*>(Wi + j*768 + k0);
      #pragma unroll
      for(int rr=0;rr<4;rr++){
        const float* h=&hrow[rh*4+rr][k0];
        facc[rr] += u.x*h[0]+u.y*h[1]+u.z*h[2]+u.w*h[3];
      }
    }
    #pragma unroll
    for(int rr=0;rr<4;rr++) projS[rh*4+rr][j]=facc[rr];
  }
  __syncthreads();
  // q = W_ih @ proj
  for(int p=0;p<12;p++){
    int task=p*256+tid;
    int r=task/384, jq=task%384;
    float acc=0.f;
    for(int k0=0;k0<128;k0+=4){
      float4 u=*reinterpret_cast<const float4*>(Wih + jq*128 + k0);
      const float* pr=&projS[r][k0];
      acc += u.x*pr[0]+u.y*pr[1]+u.z*pr[2]+u.w*pr[3];
    }
    qws[(row0+r)*384 + jq]=acc;
  }
}

// ---------------- gpre layout v3: [b][t][e][ch][4] u16 ----------------
// slot g<3: f2b( w[b,t,e]*q[g*128+ch] + bih[g*128+ch] + (g<2 ? bhh[g*128+ch] : 0) ); slot 3 pad.
__global__ __launch_bounds__(256) void k_gpre(const float* __restrict__ qws, const float* __restrict__ out,
                                              const float* __restrict__ bih, const float* __restrict__ bhh,
                                              u16* __restrict__ gpre)
{
  __shared__ float wS[8];
  __shared__ float qS[384];
  __shared__ float bS[384];
  int tid=threadIdx.x;
  int bt=blockIdx.x;
  if(tid<8) wS[tid]=out[OUT_ROUTE + bt*8 + tid];
  if(tid>=128 && tid<224){ int j=tid-128; *reinterpret_cast<float4*>(&qS[j*4]) = *reinterpret_cast<const float4*>(qws + bt*384 + j*4); }
  if(tid<96){
    int c4=tid*4;
    float4 u=*reinterpret_cast<const float4*>(bih+c4);
    if(c4<256){
      float4 v=*reinterpret_cast<const float4*>(bhh+c4);
      u.x+=v.x; u.y+=v.y; u.z+=v.z; u.w+=v.w;
    }
    *reinterpret_cast<float4*>(&bS[c4])=u;
  }
  __syncthreads();
  u16* dst = gpre + (size_t)bt*4096;
  #pragma unroll
  for(int it=0; it<4; it++){
    int cid = it*256 + tid;      // 1024 cells: e=cid>>7, ch=cid&127
    int e = cid>>7, ch = cid&127;
    float wv = wS[e];
    u16 ov[4];
    #pragma unroll
    for(int g=0; g<3; g++) ov[g]=f2b(wv*qS[g*128+ch]+bS[g*128+ch]);
    ov[3]=0;
    uint2 o; __builtin_memcpy(&o,ov,8);
    *reinterpret_cast<uint2*>(dst + cid*4) = o;
  }
}

// ---------------- sequential GRU scan, v3: 16 blocks x 4 chains, row-duplicated MFMA ----------------
// chains = (b, e0+q4), b=blk>>1, e0=(blk&1)*4. A-rows 4c..4c+3 all hold chain c
// (read hbf[il>>2] -> LDS broadcast), so C rows q4*4+i are identical and lane (q4,il)
// computes exactly ONE GRU cell: (chain q4, ch=w*16+il). 1 cell/lane => 6 trans/lane/step
// (was 24). hbf row stride 144 u16 (72 dwords = 8 mod 32) caps read conflicts at 2-way (free).
#define SCAN_SYNC asm volatile("s_waitcnt lgkmcnt(0)\n\ts_barrier" ::: "memory")

#define SCAN_STEP(BUF,NXT,P,DOLOAD)                                                         \
  {                                                                                         \
    bf16x8 af[4];                                                                           \
    _Pragma("unroll")                                                                       \
    for(int kt=0;kt<4;kt++)                                                                 \
      af[kt]=__builtin_bit_cast(bf16x8, *reinterpret_cast<const uint4*>(&hbf[BUF][il>>2][kt*32+q4*8])); \
    u16 cw[4];                                                                              \
    __builtin_memcpy(cw,&gv[P],8);                                                          \
    if(DOLOAD){                                                                             \
      gv[P]=*reinterpret_cast<const uint2*>(gp);                                            \
      gp+=4096;                                                                             \
    }                                                                                       \
    f32x4 acc0={0.f,0.f,0.f,0.f}, acc1={0.f,0.f,0.f,0.f}, acc2={0.f,0.f,0.f,0.f};           \
    _Pragma("unroll")                                                                       \
    for(int kt=0;kt<4;kt++){                                                                \
      acc0=__builtin_amdgcn_mfma_f32_16x16x32_bf16(af[kt],bfr0[kt],acc0,0,0,0);             \
      acc1=__builtin_amdgcn_mfma_f32_16x16x32_bf16(af[kt],bfr1[kt],acc1,0,0,0);             \
      acc2=__builtin_amdgcn_mfma_f32_16x16x32_bf16(af[kt],bfr2[kt],acc2,0,0,0);             \
    }                                                                                       \
    {                                                                                       \
      float r=sigf(acc0[0]+b2f(cw[0]));                                                     \
      float z=sigf(acc1[0]+b2f(cw[1]));                                                     \
      float n=tanh_(b2f(cw[2])+r*(acc2[0]+bhhn));                                           \
      float hn=n+z*(hp-n);                                                                  \
      hp=hn;                                                                                \
      u16 hb=f2b(hn);                                                                       \
      hbf[NXT][q4][ch]=hb;                                                                  \
      *sbase=hb;                                                                            \
    }                                                                                       \
    sbase += 1024;                                                                          \
    SCAN_SYNC;                                                                              \
  }

__global__ __launch_bounds__(512,1) void k_scan(const float* __restrict__ Whh, const float* __restrict__ bhh,
                                                const float* __restrict__ state0,
                                                const u16* __restrict__ gpre, u16* __restrict__ shadow)
{
  __shared__ u16 hbf[2][4][144];
  int tid=threadIdx.x;
  int w=tid>>6, L=tid&63, q4=L>>4, il=L&15;
  int blk=blockIdx.x;
  int b=blk>>1, e0=(blk&1)*4;
  int ch=w*16+il;
  // persistent B-fragments of W_hh (N=384 gate cols x K=128), cvt f32->bf16
  bf16x8 bfr0[4], bfr1[4], bfr2[4];
  #pragma unroll
  for(int kt=0; kt<4; kt++){
    u16 t0[8],t1[8],t2[8];
    #pragma unroll
    for(int j=0;j<8;j++){
      t0[j]=f2b(Whh[(0*128+ch)*128 + kt*32 + q4*8 + j]);
      t1[j]=f2b(Whh[(1*128+ch)*128 + kt*32 + q4*8 + j]);
      t2[j]=f2b(Whh[(2*128+ch)*128 + kt*32 + q4*8 + j]);
    }
    __builtin_memcpy(&bfr0[kt],t0,16);
    __builtin_memcpy(&bfr1[kt],t1,16);
    __builtin_memcpy(&bfr2[kt],t2,16);
  }
  float bhhn = bhh[256+ch];
  // this lane's single cell: chain q4 (entity e0+q4), channel ch. f32-carried h.
  float hp = state0[(e0+q4)*128+ch];
  // init bf16 h tile: 4 chains x 128 ch (rows 128..143 unused)
  {
    int cc=tid>>7, chh=tid&127;
    hbf[0][cc][chh]=f2b(state0[(e0+cc)*128+chh]);
  }
  // per-lane streaming pointers (gpre v3 layout)
  const u16* gp = gpre + (size_t)b*1024*4096 + ((e0+q4)*128+ch)*4;
  u16* sbase = shadow + ((size_t)b*1024*8 + (e0+q4))*128 + ch;
  // distance-4 prefetch (statically indexed slots)
  uint2 gv[4];
  #pragma unroll
  for(int p=0;p<4;p++){
    gv[p]=*reinterpret_cast<const uint2*>(gp);
    gp+=4096;
  }
  SCAN_SYNC;
  #pragma unroll 1
  for(int t2=0;t2<255;t2++){
    SCAN_STEP(0,1,0,1)
    SCAN_STEP(1,0,1,1)
    SCAN_STEP(0,1,2,1)
    SCAN_STEP(1,0,3,1)
  }
  // epilogue: last 4 steps, no prefetch
  SCAN_STEP(0,1,0,0)
  SCAN_STEP(1,0,1,0)
  SCAN_STEP(0,1,2,0)
  SCAN_STEP(1,0,3,0)
}

// ---------------- expand bf16 shadow -> f32 OUT_STATE ----------------
__global__ __launch_bounds__(256) void k_expand(const u16* __restrict__ sh, float* __restrict__ o)
{
  int idx=(blockIdx.x*256+threadIdx.x)*4;
  uint2 u=*reinterpret_cast<const uint2*>(sh+idx);
  float4 f;
  f.x=b2f((u16)(u.x&0xffffu)); f.y=b2f((u16)(u.x>>16));
  f.z=b2f((u16)(u.y&0xffffu)); f.w=b2f((u16)(u.y>>16));
  *reinterpret_cast<float4*>(o+idx)=f;
}

// ---------------- memory_stack + head hidden (GEMM [65536x128]@[128x960]) ----------------
__global__ __launch_bounds__(256) void k_mem(const u16* __restrict__ state, const u16* __restrict__ wcat,
                                             const float* __restrict__ bcat,
                                             float* __restrict__ memout, u16* __restrict__ hdn)
{
  __shared__ u16 As[128][136];
  __shared__ u16 Bs[96][136];
  int tid=threadIdx.x;
  int bx=blockIdx.x, ny=blockIdx.y;
  for(int it=0;it<8;it++){
    int v=it*256+tid; int r=v>>4, c8=(v&15)*8;
    *reinterpret_cast<uint4*>(&As[r][c8]) = *reinterpret_cast<const uint4*>(state + (bx*128+r)*128 + c8);
  }
  for(int it=0;it<6;it++){
    int v=it*256+tid; int r=v>>4, c8=(v&15)*8;
    *reinterpret_cast<uint4*>(&Bs[r][c8]) = *reinterpret_cast<const uint4*>(wcat + (ny*96+r)*128 + c8);
  }
  __syncthreads();
  int w=tid>>6, L=tid&63, q4=L>>4, il=L&15;
  int msub=w*32;
  bf16x8 af[2][4];
  #pragma unroll
  for(int tm=0;tm<2;tm++)
    #pragma unroll
    for(int kt=0;kt<4;kt++)
      af[tm][kt]=__builtin_bit_cast(bf16x8,*reinterpret_cast<const uint4*>(&As[msub+tm*16+il][kt*32+q4*8]));
  const f32x4 fz = {0.f,0.f,0.f,0.f};
  f32x4 acc[2][6];
  #pragma unroll
  for(int tm=0;tm<2;tm++){
    #pragma unroll
    for(int tn=0;tn<6;tn++) acc[tm][tn]=fz;
  }
  #pragma unroll
  for(int tn=0;tn<6;tn++){
    bf16x8 bf[4];
    #pragma unroll
    for(int kt=0;kt<4;kt++)
      bf[kt]=__builtin_bit_cast(bf16x8,*reinterpret_cast<const uint4*>(&Bs[tn*16+il][kt*32+q4*8]));
    #pragma unroll
    for(int tm=0;tm<2;tm++){
      #pragma unroll
      for(int kt=0;kt<4;kt++)
        acc[tm][tn]=__builtin_amdgcn_mfma_f32_16x16x32_bf16(af[tm][kt],bf[kt],acc[tm][tn],0,0,0);
    }
  }
  #pragma unroll
  for(int tm=0;tm<2;tm++){
    #pragma unroll
    for(int tn=0;tn<6;tn++){
      int col=ny*96+tn*16+il;
      float bias=bcat[col];
      #pragma unroll
      for(int i=0;i<4;i++){
        int row=bx*128+msub+tm*16+q4*4+i;
        float val=acc[tm][tn][i]+bias;
        if(ny<8) memout[row*768+col]=val;
        else hdn[row*192+(col-768)]=f2b(geluf(val));
      }
    }
  }
}

// ---------------- pooled = state_flat[8192x1024] @ Wcomb.T + b_comb ----------------
__global__ __launch_bounds__(256) void k_pool(const u16* __restrict__ state, const u16* __restrict__ wcomb,
                                              const float* __restrict__ bcomb, float* __restrict__ pooled)
{
  __shared__ u16 As[128][136];
  __shared__ u16 Bs[96][136];
  int tid=threadIdx.x;
  int bx=blockIdx.x, ny=blockIdx.y;
  int w=tid>>6, L=tid&63, q4=L>>4, il=L&15;
  int msub=w*32;
  const f32x4 fz = {0.f,0.f,0.f,0.f};
  f32x4 acc[2][6];
  #pragma unroll
  for(int tm=0;tm<2;tm++){
    #pragma unroll
    for(int tn=0;tn<6;tn++) acc[tm][tn]=fz;
  }
  for(int kc=0;kc<8;kc++){
    __syncthreads();
    for(int it=0;it<8;it++){
      int v=it*256+tid; int r=v>>4, c8=(v&15)*8;
      *reinterpret_cast<uint4*>(&As[r][c8]) = *reinterpret_cast<const uint4*>(state + (bx*128+r)*1024 + kc*128 + c8);
    }
    for(int it=0;it<6;it++){
      int v=it*256+tid; int r=v>>4, c8=(v&15)*8;
      *reinterpret_cast<uint4*>(&Bs[r][c8]) = *reinterpret_cast<const uint4*>(wcomb + (ny*96+r)*1024 + kc*128 + c8);
    }
    __syncthreads();
    bf16x8 af[2][4];
    #pragma unroll
    for(int tm=0;tm<2;tm++)
      #pragma unroll
      for(int kt=0;kt<4;kt++)
        af[tm][kt]=__builtin_bit_cast(bf16x8,*reinterpret_cast<const uint4*>(&As[msub+tm*16+il][kt*32+q4*8]));
    #pragma unroll
    for(int tn=0;tn<6;tn++){
      bf16x8 bf[4];
      #pragma unroll
      for(int kt=0;kt<4;kt++)
        bf[kt]=__builtin_bit_cast(bf16x8,*reinterpret_cast<const uint4*>(&Bs[tn*16+il][kt*32+q4*8]));
      #pragma unroll
      for(int tm=0;tm<2;tm++){
        #pragma unroll
        for(int kt=0;kt<4;kt++)
          acc[tm][tn]=__builtin_amdgcn_mfma_f32_16x16x32_bf16(af[tm][kt],bf[kt],acc[tm][tn],0,0,0);
      }
    }
  }
  #pragma unroll
  for(int tm=0;tm<2;tm++){
    #pragma unroll
    for(int tn=0;tn<6;tn++){
      int col=ny*96+tn*16+il;
      float bias=bcomb[col];
      #pragma unroll
      for(int i=0;i<4;i++){
        int row=bx*128+msub+tm*16+q4*4+i;
        pooled[row*768+col]=acc[tm][tn][i]+bias;
      }
    }
  }
}

// ---------------- head second layer ----------------
__global__ __launch_bounds__(256) void k_heads(const u16* __restrict__ hdn,
                                               const float* __restrict__ Wh2, const float* __restrict__ bh2,
                                               const float* __restrict__ Wt2, const float* __restrict__ bt2,
                                               const float* __restrict__ Wv2, const float* __restrict__ bv2,
                                               float* __restrict__ out)
{
  int oid=blockIdx.x*256+threadIdx.x;
  int row=oid&65535, head=oid>>16;
  const float* w2 = (head==0)?Wh2:(head==1)?Wt2:Wv2;
  float b2 = ((head==0)?bh2:(head==1)?bt2:bv2)[0];
  float acc=0.f;
  const u16* src = hdn + row*192 + head*64;
  for(int j0=0;j0<64;j0+=8){
    uint4 hu=*reinterpret_cast<const uint4*>(src+j0);
    u16 hs[8]; __builtin_memcpy(hs,&hu,16);
    #pragma unroll
    for(int j=0;j<8;j++) acc+=b2f(hs[j])*w2[j0+j];
  }
  out[OUT_HOLD + head*65536 + row]=acc+b2;
}

extern "C" void kernel_launch(void* const* d_in, const int* in_sizes, int n_in,
                              void* d_out, int out_size, void* d_ws, size_t ws_size,
                              hipStream_t stream)
{
  const float* hseq=(const float*)d_in[0];
  const float* ek  =(const float*)d_in[1];
  const float* st0 =(const float*)d_in[2];
  const float* Wi  =(const float*)d_in[3];
  const float* bi  =(const float*)d_in[4];
  const float* Wih =(const float*)d_in[5];
  const float* Whh =(const float*)d_in[6];
  const float* bih =(const float*)d_in[7];
  const float* bhh =(const float*)d_in[8];
  const float* Wm  =(const float*)d_in[9];
  const float* bm  =(const float*)d_in[10];
  const float* Ws  =(const float*)d_in[11];
  const float* bs  =(const float*)d_in[12];
  const float* Wh1 =(const float*)d_in[13];
  const float* bh1 =(const float*)d_in[14];
  const float* Wh2 =(const float*)d_in[15];
  const float* bh2 =(const float*)d_in[16];
  const float* Wt1 =(const float*)d_in[17];
  const float* bt1 =(const float*)d_in[18];
  const float* Wt2 =(const float*)d_in[19];
  const float* bt2 =(const float*)d_in[20];
  const float* Wv1 =(const float*)d_in[21];
  const float* bv1 =(const float*)d_in[22];
  const float* Wv2 =(const float*)d_in[23];
  const float* bv2 =(const float*)d_in[24];
  float* out=(float*)d_out;
  char* ws=(char*)d_ws;
  // layout v3 (peak 98.3 MB, below prior 106.7 MB):
  float* qws  =(float*)ws;                 // [0, 12,582,912)           12.6 MB, dead after k_gpre
  u16*  gpre  =(u16*)(ws+12582912);        // [12,582,912, 79,691,776)  64 MB,  dead after k_scan
  u16*  wcomb =(u16*)(ws+79691776);        // 1,572,864 -> 81,264,640
  float* bcomb=(float*)(ws+81264640);      // 3,072     -> 81,267,712
  u16*  wcat  =(u16*)(ws+81267712);        // 245,760   -> 81,513,472
  float* bcat =(float*)(ws+81513472);      // 3,840     -> 81,517,312
  u16*  shadow=(u16*)(ws+81517312);        // 16,777,216 -> 98,294,528
  u16*  hdn   =(u16*)(ws+12582912);        // 25 MB, OVERLAPS dead qws/gpre head (k_mem > k_scan order)

  hipLaunchKernelGGL(k_prep, dim3(192), dim3(256), 0, stream,
                     Ws,bs,bm,Wm,Wh1,bh1,Wt1,bt1,Wv1,bv1,wcat,bcat,bcomb);
  hipLaunchKernelGGL(k_wcomb, dim3(96), dim3(256), 0, stream, Ws,Wm,wcomb);
  hipLaunchKernelGGL(k_route, dim3(1024), dim3(256), 0, stream, hseq,ek,Wi,bi,Wih,qws,out);
  hipLaunchKernelGGL(k_gpre, dim3(8192), dim3(256), 0, stream, qws,out,bih,bhh,gpre);
  hipLaunchKernelGGL(k_scan, dim3(16), dim3(512), 0, stream, Whh,bhh,st0,gpre,shadow);
  hipLaunchKernelGGL(k_expand, dim3(8192), dim3(256), 0, stream, shadow,out+OUT_STATE);
  hipLaunchKernelGGL(k_mem, dim3(512,10), dim3(256), 0, stream, shadow,wcat,bcat,out+OUT_MEM,hdn);
  hipLaunchKernelGGL(k_pool, dim3(64,8), dim3(256), 0, stream, shadow,wcomb,bcomb,out+OUT_POOLED);
  hipLaunchKernelGGL(k_heads, dim3(768), dim3(256), 0, stream, hdn,Wh2,bh2,Wt2,bt2,Wv2,bv2,out);
}

// Round 3
// 1170.088 us; speedup vs baseline: 1.5859x; 1.0942x over previous
//
#include <hip/hip_runtime.h>
#include <hip/hip_bf16.h>

typedef unsigned short u16;
typedef unsigned int u32;
typedef __bf16 bf16x8 __attribute__((ext_vector_type(8)));
typedef float f32x4 __attribute__((ext_vector_type(4)));

// output element offsets (f32 elements)
#define OUT_POOLED 0
#define OUT_MEM    6291456
#define OUT_STATE  56623104
#define OUT_HOLD   65011712
#define OUT_ROUTE  65208320

__device__ __forceinline__ float b2f(u16 u){ u32 v=((u32)u)<<16; float f; __builtin_memcpy(&f,&v,4); return f; }
__device__ __forceinline__ u16 f2b(float f){ __hip_bfloat16 h=__float2bfloat16(f); u16 r; __builtin_memcpy(&r,&h,2); return r; }
__device__ __forceinline__ float sigf(float x){ return __builtin_amdgcn_rcpf(1.0f+__builtin_amdgcn_exp2f(-1.4426950408889634f*x)); }
__device__ __forceinline__ float tanh_(float x){ return 1.0f-2.0f*__builtin_amdgcn_rcpf(1.0f+__builtin_amdgcn_exp2f(2.8853900817779268f*x)); }
__device__ __forceinline__ float geluf(float x){
  float z = 0.7071067811865476f*x;
  float az = __builtin_fabsf(z);
  float t = __builtin_amdgcn_rcpf(1.0f+0.3275911f*az);
  float p = t*(0.254829592f+t*(-0.284496736f+t*(1.421413741f+t*(-1.453152027f+t*1.061405429f))));
  float e = __builtin_amdgcn_exp2f(-1.4426950408889634f*az*az);
  float er = 1.0f-p*e;
  er = (z<0.0f)? -er : er;
  return 0.5f*x*(1.0f+er);
}

// ---------------- prep: wcat pack (bf16), bcat, b_comb ----------------
__global__ void k_prep(const float* __restrict__ Ws, const float* __restrict__ bs,
                       const float* __restrict__ bm, const float* __restrict__ Wm,
                       const float* __restrict__ Wh1, const float* __restrict__ bh1,
                       const float* __restrict__ Wt1, const float* __restrict__ bt1,
                       const float* __restrict__ Wv1, const float* __restrict__ bv1,
                       u16* __restrict__ wcat, float* __restrict__ bcat, float* __restrict__ bcomb)
{
  __shared__ float bmS[768];
  int tid = threadIdx.x;
  for(int i=tid;i<768;i+=256) bmS[i]=bm[i];
  __syncthreads();
  // bcomb: grid 192 x 4 waves, one wave per d
  {
    int w = tid>>6, lane = tid&63;
    int d = blockIdx.x*4 + w;
    float acc=0.f;
    for(int e=0;e<8;e++){
      const float* row = Ws + (size_t)d*6144 + e*768;
      #pragma unroll
      for(int it=0; it<3; it++){
        int c = it*256 + lane*4;
        float4 u = *reinterpret_cast<const float4*>(row + c);
        acc += u.x*bmS[c]+u.y*bmS[c+1]+u.z*bmS[c+2]+u.w*bmS[c+3];
      }
    }
    #pragma unroll
    for(int o=32;o>0;o>>=1) acc += __shfl_down(acc,o);
    if(lane==0) bcomb[d]=bs[d]+acc;
  }
  // bcat (960) + wcat (122880)
  for(int idx = blockIdx.x*256+tid; idx<123840; idx += gridDim.x*256){
    if(idx<960){
      int n=idx;
      float v;
      if(n<768) v=bm[n];
      else { int j=n-768; v = (j<64)? bh1[j] : (j<128)? bt1[j-64] : bv1[j-128]; }
      bcat[n]=v;
    } else {
      int c=idx-960; int n=c>>7, k=c&127;
      float v;
      if(n<768) v=Wm[n*128+k];
      else if(n<832) v=Wh1[(n-768)*128+k];
      else if(n<896) v=Wt1[(n-832)*128+k];
      else v=Wv1[(n-896)*128+k];
      wcat[c]=f2b(v);
    }
  }
}

// ---------------- Wcomb[d][e*128+s] = sum_d2 Ws[d][e*768+d2]*Wm[d2][s] (bf16 out) ----------------
__global__ __launch_bounds__(256) void k_wcomb(const float* __restrict__ Ws, const float* __restrict__ Wm,
                                               u16* __restrict__ wcomb)
{
  __shared__ float WmS[96][128];
  __shared__ float WsS[64][96];
  int tid=threadIdx.x;
  int e = blockIdx.x/12, dt = blockIdx.x%12;
  int d0 = dt*64;
  int s = tid&127, dh = tid>>7;
  float acc[32];
  #pragma unroll
  for(int i=0;i<32;i++) acc[i]=0.f;
  for(int c=0;c<8;c++){
    int c0=c*96;
    __syncthreads();
    for(int it=0; it<12; it++){
      int v=it*256+tid; int r=v>>5, c4=(v&31)*4;
      *reinterpret_cast<float4*>(&WmS[r][c4]) = *reinterpret_cast<const float4*>(Wm + (c0+r)*128 + c4);
    }
    for(int it=0; it<6; it++){
      int v=it*256+tid; int dl=v/24, c4=(v%24)*4;
      *reinterpret_cast<float4*>(&WsS[dl][c4]) = *reinterpret_cast<const float4*>(Ws + (d0+dl)*6144 + e*768 + c0 + c4);
    }
    __syncthreads();
    for(int d2=0; d2<96; d2++){
      float wm = WmS[d2][s];
      #pragma unroll
      for(int ds=0; ds<32; ds++) acc[ds] += WsS[dh*32+ds][d2]*wm;
    }
  }
  for(int ds=0; ds<32; ds++){
    int d = d0 + dh*32 + ds;
    wcomb[d*1024 + e*128 + s] = f2b(acc[ds]);
  }
}

// ---------------- routing softmax + q = W_ih@(Wi@h + bi) + gpre emit (fused) ----------------
// v4: (1) batched global loads (8 float4 in flight) to hide L2 latency (was VGPR=52,
//     2-3 in flight, VALUBusy 12.7%); (2) logits parallelized over all 256 threads;
//     (3) k_gpre fused: q parked in LDS (aliases dead hrow), gpre written directly.
#define HR 772
__global__ __launch_bounds__(256,4) void k_route(const float* __restrict__ hseq, const float* __restrict__ ek,
                                               const float* __restrict__ Wi, const float* __restrict__ bi,
                                               const float* __restrict__ Wih,
                                               const float* __restrict__ bih, const float* __restrict__ bhh,
                                               u16* __restrict__ gpre, float* __restrict__ out)
{
  __shared__ float hrow[8][HR];      // after q-phase, first 3072 floats alias as qS[8][384]
  __shared__ float projS[8][128];
  __shared__ float lgsP[64][4];
  __shared__ float bS[384];
  __shared__ float wSm[8][8];
  int tid=threadIdx.x;
  int row0 = blockIdx.x*8;
  for(int it=0; it<6; it++){
    int v=it*256+tid; int r=v/192, c4=(v%192)*4;
    *reinterpret_cast<float4*>(&hrow[r][c4]) = *reinterpret_cast<const float4*>(hseq + (row0+r)*768 + c4);
  }
  __syncthreads();   // S1
  // logits partials: dot=tid>>2 (r=dot>>3, e=dot&7), seg=tid&3 covers 192 k each
  {
    int dot=tid>>2, seg=tid&3;
    int r=dot>>3, e=dot&7;
    const float* er = ek + e*768 + seg*192;
    const float* h  = &hrow[r][seg*192];
    float a0=0.f, a1=0.f;
    for(int k0=0;k0<192;k0+=32){
      float4 u[8];
      #pragma unroll
      for(int m=0;m<8;m++) u[m]=*reinterpret_cast<const float4*>(er+k0+m*4);
      #pragma unroll
      for(int m=0;m<8;m++){
        const float* hh=h+k0+m*4;
        float c=u[m].x*hh[0]+u[m].y*hh[1]+u[m].z*hh[2]+u[m].w*hh[3];
        if(m&1) a1+=c; else a0+=c;
      }
    }
    lgsP[dot][seg]=a0+a1;
  }
  // proj = Wi@h + bi (batched Wi loads)
  {
    int j=tid&127, rh=tid>>7;
    float facc[4];
    float bj=bi[j];
    #pragma unroll
    for(int rr=0;rr<4;rr++) facc[rr]=bj;
    const float* wrow = Wi + j*768;
    for(int k0=0;k0<768;k0+=32){
      float4 u[8];
      #pragma unroll
      for(int m=0;m<8;m++) u[m]=*reinterpret_cast<const float4*>(wrow + k0 + m*4);
      #pragma unroll
      for(int m=0;m<8;m++){
        #pragma unroll
        for(int rr=0;rr<4;rr++){
          const float* h=&hrow[rh*4+rr][k0+m*4];
          facc[rr] += u[m].x*h[0]+u[m].y*h[1]+u[m].z*h[2]+u[m].w*h[3];
        }
      }
    }
    #pragma unroll
    for(int rr=0;rr<4;rr++) projS[rh*4+rr][j]=facc[rr];
  }
  __syncthreads();   // S2 (lgsP + projS ready; hrow dead after this point)
  // softmax (tid<8) ; bias staging (tid 64..159) ; q compute (all)
  if(tid<8){
    int r=tid;
    float l[8], m=-1e30f;
    #pragma unroll
    for(int e=0;e<8;e++){
      float* p=lgsP[r*8+e];
      l[e]=(p[0]+p[1]+p[2]+p[3]) * (1.0f/27.712812921102035f);
      m=fmaxf(m,l[e]);
    }
    float s=0.f;
    #pragma unroll
    for(int e=0;e<8;e++){ l[e]=__builtin_amdgcn_exp2f(1.4426950408889634f*(l[e]-m)); s+=l[e]; }
    float inv=__builtin_amdgcn_rcpf(s);
    #pragma unroll
    for(int e=0;e<8;e++){
      float wv=l[e]*inv;
      wSm[r][e]=wv;
      out[OUT_ROUTE + (row0+r)*8 + e] = wv;
    }
  }
  if(tid>=64 && tid<160){
    int j4=(tid-64)*4;
    float4 u=*reinterpret_cast<const float4*>(bih+j4);
    if(j4<256){
      float4 v=*reinterpret_cast<const float4*>(bhh+j4);
      u.x+=v.x; u.y+=v.y; u.z+=v.z; u.w+=v.w;
    }
    *reinterpret_cast<float4*>(&bS[j4])=u;
  }
  // q = W_ih @ proj -> qS (aliases hrow)
  {
    float* qS = &hrow[0][0];
    for(int p=0;p<12;p++){
      int task=p*256+tid;
      int r=task/384, jq=task-r*384;
      const float* wrow = Wih + jq*128;
      const float* pr = projS[r];
      float a0=0.f,a1=0.f;
      #pragma unroll
      for(int k0=0;k0<128;k0+=32){
        float4 u[8];
        #pragma unroll
        for(int m=0;m<8;m++) u[m]=*reinterpret_cast<const float4*>(wrow+k0+m*4);
        #pragma unroll
        for(int m=0;m<8;m++){
          const float* pp=pr+k0+m*4;
          float c=u[m].x*pp[0]+u[m].y*pp[1]+u[m].z*pp[2]+u[m].w*pp[3];
          if(m&1) a1+=c; else a0+=c;
        }
      }
      qS[r*384+jq]=a0+a1;
    }
  }
  __syncthreads();   // S3
  // gpre emit: 8192 cells (8 rows x 1024), cell=(e,ch), 4 u16 each: [r][e][ch][{g0,g1,g2,pad}]
  {
    const float* qS = &hrow[0][0];
    #pragma unroll
    for(int it=0; it<32; it++){
      int cellIdx = it*256 + tid;
      int r = cellIdx>>10, cid = cellIdx&1023;
      int e = cid>>7, ch = cid&127;
      float wv = wSm[r][e];
      const float* q = qS + r*384;
      u16 ov[4];
      #pragma unroll
      for(int g=0; g<3; g++) ov[g]=f2b(wv*q[g*128+ch]+bS[g*128+ch]);
      ov[3]=0;
      uint2 o; __builtin_memcpy(&o,ov,8);
      *reinterpret_cast<uint2*>(gpre + (size_t)(row0+r)*4096 + cid*4) = o;
    }
  }
}

// ---------------- sequential GRU scan, v3: 16 blocks x 4 chains, row-duplicated MFMA ----------------
#define SCAN_SYNC asm volatile("s_waitcnt lgkmcnt(0)\n\ts_barrier" ::: "memory")

#define SCAN_STEP(BUF,NXT,P,DOLOAD)                                                         \
  {                                                                                         \
    bf16x8 af[4];                                                                           \
    _Pragma("unroll")                                                                       \
    for(int kt=0;kt<4;kt++)                                                                 \
      af[kt]=__builtin_bit_cast(bf16x8, *reinterpret_cast<const uint4*>(&hbf[BUF][il>>2][kt*32+q4*8])); \
    u16 cw[4];                                                                              \
    __builtin_memcpy(cw,&gv[P],8);                                                          \
    if(DOLOAD){                                                                             \
      gv[P]=*reinterpret_cast<const uint2*>(gp);                                            \
      gp+=4096;                                                                             \
    }                                                                                       \
    f32x4 acc0={0.f,0.f,0.f,0.f}, acc1={0.f,0.f,0.f,0.f}, acc2={0.f,0.f,0.f,0.f};           \
    _Pragma("unroll")                                                                       \
    for(int kt=0;kt<4;kt++){                                                                \
      acc0=__builtin_amdgcn_mfma_f32_16x16x32_bf16(af[kt],bfr0[kt],acc0,0,0,0);             \
      acc1=__builtin_amdgcn_mfma_f32_16x16x32_bf16(af[kt],bfr1[kt],acc1,0,0,0);             \
      acc2=__builtin_amdgcn_mfma_f32_16x16x32_bf16(af[kt],bfr2[kt],acc2,0,0,0);             \
    }                                                                                       \
    {                                                                                       \
      float r=sigf(acc0[0]+b2f(cw[0]));                                                     \
      float z=sigf(acc1[0]+b2f(cw[1]));                                                     \
      float n=tanh_(b2f(cw[2])+r*(acc2[0]+bhhn));                                           \
      float hn=n+z*(hp-n);                                                                  \
      hp=hn;                                                                                \
      u16 hb=f2b(hn);                                                                       \
      hbf[NXT][q4][ch]=hb;                                                                  \
      *sbase=hb;                                                                            \
    }                                                                                       \
    sbase += 1024;                                                                          \
    SCAN_SYNC;                                                                              \
  }

__global__ __launch_bounds__(512,1) void k_scan(const float* __restrict__ Whh, const float* __restrict__ bhh,
                                                const float* __restrict__ state0,
                                                const u16* __restrict__ gpre, u16* __restrict__ shadow)
{
  __shared__ u16 hbf[2][4][144];
  int tid=threadIdx.x;
  int w=tid>>6, L=tid&63, q4=L>>4, il=L&15;
  int blk=blockIdx.x;
  int b=blk>>1, e0=(blk&1)*4;
  int ch=w*16+il;
  bf16x8 bfr0[4], bfr1[4], bfr2[4];
  #pragma unroll
  for(int kt=0; kt<4; kt++){
    u16 t0[8],t1[8],t2[8];
    #pragma unroll
    for(int j=0;j<8;j++){
      t0[j]=f2b(Whh[(0*128+ch)*128 + kt*32 + q4*8 + j]);
      t1[j]=f2b(Whh[(1*128+ch)*128 + kt*32 + q4*8 + j]);
      t2[j]=f2b(Whh[(2*128+ch)*128 + kt*32 + q4*8 + j]);
    }
    __builtin_memcpy(&bfr0[kt],t0,16);
    __builtin_memcpy(&bfr1[kt],t1,16);
    __builtin_memcpy(&bfr2[kt],t2,16);
  }
  float bhhn = bhh[256+ch];
  float hp = state0[(e0+q4)*128+ch];
  {
    int cc=tid>>7, chh=tid&127;
    hbf[0][cc][chh]=f2b(state0[(e0+cc)*128+chh]);
  }
  const u16* gp = gpre + (size_t)b*1024*4096 + ((e0+q4)*128+ch)*4;
  u16* sbase = shadow + ((size_t)b*1024*8 + (e0+q4))*128 + ch;
  uint2 gv[4];
  #pragma unroll
  for(int p=0;p<4;p++){
    gv[p]=*reinterpret_cast<const uint2*>(gp);
    gp+=4096;
  }
  SCAN_SYNC;
  #pragma unroll 1
  for(int t2=0;t2<255;t2++){
    SCAN_STEP(0,1,0,1)
    SCAN_STEP(1,0,1,1)
    SCAN_STEP(0,1,2,1)
    SCAN_STEP(1,0,3,1)
  }
  SCAN_STEP(0,1,0,0)
  SCAN_STEP(1,0,1,0)
  SCAN_STEP(0,1,2,0)
  SCAN_STEP(1,0,3,0)
}

// ---------------- expand bf16 shadow -> f32 OUT_STATE ----------------
__global__ __launch_bounds__(256) void k_expand(const u16* __restrict__ sh, float* __restrict__ o)
{
  int idx=(blockIdx.x*256+threadIdx.x)*4;
  uint2 u=*reinterpret_cast<const uint2*>(sh+idx);
  float4 f;
  f.x=b2f((u16)(u.x&0xffffu)); f.y=b2f((u16)(u.x>>16));
  f.z=b2f((u16)(u.y&0xffffu)); f.w=b2f((u16)(u.y>>16));
  *reinterpret_cast<float4*>(o+idx)=f;
}

// ---------------- memory_stack + head hidden (GEMM [65536x128]@[128x960]) ----------------
__global__ __launch_bounds__(256) void k_mem(const u16* __restrict__ state, const u16* __restrict__ wcat,
                                             const float* __restrict__ bcat,
                                             float* __restrict__ memout, u16* __restrict__ hdn)
{
  __shared__ u16 As[128][136];
  __shared__ u16 Bs[96][136];
  int tid=threadIdx.x;
  int bx=blockIdx.x, ny=blockIdx.y;
  for(int it=0;it<8;it++){
    int v=it*256+tid; int r=v>>4, c8=(v&15)*8;
    *reinterpret_cast<uint4*>(&As[r][c8]) = *reinterpret_cast<const uint4*>(state + (bx*128+r)*128 + c8);
  }
  for(int it=0;it<6;it++){
    int v=it*256+tid; int r=v>>4, c8=(v&15)*8;
    *reinterpret_cast<uint4*>(&Bs[r][c8]) = *reinterpret_cast<const uint4*>(wcat + (ny*96+r)*128 + c8);
  }
  __syncthreads();
  int w=tid>>6, L=tid&63, q4=L>>4, il=L&15;
  int msub=w*32;
  bf16x8 af[2][4];
  #pragma unroll
  for(int tm=0;tm<2;tm++)
    #pragma unroll
    for(int kt=0;kt<4;kt++)
      af[tm][kt]=__builtin_bit_cast(bf16x8,*reinterpret_cast<const uint4*>(&As[msub+tm*16+il][kt*32+q4*8]));
  const f32x4 fz = {0.f,0.f,0.f,0.f};
  f32x4 acc[2][6];
  #pragma unroll
  for(int tm=0;tm<2;tm++){
    #pragma unroll
    for(int tn=0;tn<6;tn++) acc[tm][tn]=fz;
  }
  #pragma unroll
  for(int tn=0;tn<6;tn++){
    bf16x8 bf[4];
    #pragma unroll
    for(int kt=0;kt<4;kt++)
      bf[kt]=__builtin_bit_cast(bf16x8,*reinterpret_cast<const uint4*>(&Bs[tn*16+il][kt*32+q4*8]));
    #pragma unroll
    for(int tm=0;tm<2;tm++){
      #pragma unroll
      for(int kt=0;kt<4;kt++)
        acc[tm][tn]=__builtin_amdgcn_mfma_f32_16x16x32_bf16(af[tm][kt],bf[kt],acc[tm][tn],0,0,0);
    }
  }
  #pragma unroll
  for(int tm=0;tm<2;tm++){
    #pragma unroll
    for(int tn=0;tn<6;tn++){
      int col=ny*96+tn*16+il;
      float bias=bcat[col];
      #pragma unroll
      for(int i=0;i<4;i++){
        int row=bx*128+msub+tm*16+q4*4+i;
        float val=acc[tm][tn][i]+bias;
        if(ny<8) memout[row*768+col]=val;
        else hdn[row*192+(col-768)]=f2b(geluf(val));
      }
    }
  }
}

// ---------------- pooled = state_flat[8192x1024] @ Wcomb.T + b_comb ----------------
__global__ __launch_bounds__(256) void k_pool(const u16* __restrict__ state, const u16* __restrict__ wcomb,
                                              const float* __restrict__ bcomb, float* __restrict__ pooled)
{
  __shared__ u16 As[128][136];
  __shared__ u16 Bs[96][136];
  int tid=threadIdx.x;
  int bx=blockIdx.x, ny=blockIdx.y;
  int w=tid>>6, L=tid&63, q4=L>>4, il=L&15;
  int msub=w*32;
  const f32x4 fz = {0.f,0.f,0.f,0.f};
  f32x4 acc[2][6];
  #pragma unroll
  for(int tm=0;tm<2;tm++){
    #pragma unroll
    for(int tn=0;tn<6;tn++) acc[tm][tn]=fz;
  }
  for(int kc=0;kc<8;kc++){
    __syncthreads();
    for(int it=0;it<8;it++){
      int v=it*256+tid; int r=v>>4, c8=(v&15)*8;
      *reinterpret_cast<uint4*>(&As[r][c8]) = *reinterpret_cast<const uint4*>(state + (bx*128+r)*1024 + kc*128 + c8);
    }
    for(int it=0;it<6;it++){
      int v=it*256+tid; int r=v>>4, c8=(v&15)*8;
      *reinterpret_cast<uint4*>(&Bs[r][c8]) = *reinterpret_cast<const uint4*>(wcomb + (ny*96+r)*1024 + kc*128 + c8);
    }
    __syncthreads();
    bf16x8 af[2][4];
    #pragma unroll
    for(int tm=0;tm<2;tm++)
      #pragma unroll
      for(int kt=0;kt<4;kt++)
        af[tm][kt]=__builtin_bit_cast(bf16x8,*reinterpret_cast<const uint4*>(&As[msub+tm*16+il][kt*32+q4*8]));
    #pragma unroll
    for(int tn=0;tn<6;tn++){
      bf16x8 bf[4];
      #pragma unroll
      for(int kt=0;kt<4;kt++)
        bf[kt]=__builtin_bit_cast(bf16x8,*reinterpret_cast<const uint4*>(&Bs[tn*16+il][kt*32+q4*8]));
      #pragma unroll
      for(int tm=0;tm<2;tm++){
        #pragma unroll
        for(int kt=0;kt<4;kt++)
          acc[tm][tn]=__builtin_amdgcn_mfma_f32_16x16x32_bf16(af[tm][kt],bf[kt],acc[tm][tn],0,0,0);
      }
    }
  }
  #pragma unroll
  for(int tm=0;tm<2;tm++){
    #pragma unroll
    for(int tn=0;tn<6;tn++){
      int col=ny*96+tn*16+il;
      float bias=bcomb[col];
      #pragma unroll
      for(int i=0;i<4;i++){
        int row=bx*128+msub+tm*16+q4*4+i;
        pooled[row*768+col]=acc[tm][tn][i]+bias;
      }
    }
  }
}

// ---------------- head second layer ----------------
__global__ __launch_bounds__(256) void k_heads(const u16* __restrict__ hdn,
                                               const float* __restrict__ Wh2, const float* __restrict__ bh2,
                                               const float* __restrict__ Wt2, const float* __restrict__ bt2,
                                               const float* __restrict__ Wv2, const float* __restrict__ bv2,
                                               float* __restrict__ out)
{
  int oid=blockIdx.x*256+threadIdx.x;
  int row=oid&65535, head=oid>>16;
  const float* w2 = (head==0)?Wh2:(head==1)?Wt2:Wv2;
  float b2 = ((head==0)?bh2:(head==1)?bt2:bv2)[0];
  float acc=0.f;
  const u16* src = hdn + row*192 + head*64;
  for(int j0=0;j0<64;j0+=8){
    uint4 hu=*reinterpret_cast<const uint4*>(src+j0);
    u16 hs[8]; __builtin_memcpy(hs,&hu,16);
    #pragma unroll
    for(int j=0;j<8;j++) acc+=b2f(hs[j])*w2[j0+j];
  }
  out[OUT_HOLD + head*65536 + row]=acc+b2;
}

extern "C" void kernel_launch(void* const* d_in, const int* in_sizes, int n_in,
                              void* d_out, int out_size, void* d_ws, size_t ws_size,
                              hipStream_t stream)
{
  const float* hseq=(const float*)d_in[0];
  const float* ek  =(const float*)d_in[1];
  const float* st0 =(const float*)d_in[2];
  const float* Wi  =(const float*)d_in[3];
  const float* bi  =(const float*)d_in[4];
  const float* Wih =(const float*)d_in[5];
  const float* Whh =(const float*)d_in[6];
  const float* bih =(const float*)d_in[7];
  const float* bhh =(const float*)d_in[8];
  const float* Wm  =(const float*)d_in[9];
  const float* bm  =(const float*)d_in[10];
  const float* Ws  =(const float*)d_in[11];
  const float* bs  =(const float*)d_in[12];
  const float* Wh1 =(const float*)d_in[13];
  const float* bh1 =(const float*)d_in[14];
  const float* Wh2 =(const float*)d_in[15];
  const float* bh2 =(const float*)d_in[16];
  const float* Wt1 =(const float*)d_in[17];
  const float* bt1 =(const float*)d_in[18];
  const float* Wt2 =(const float*)d_in[19];
  const float* bt2 =(const float*)d_in[20];
  const float* Wv1 =(const float*)d_in[21];
  const float* bv1 =(const float*)d_in[22];
  const float* Wv2 =(const float*)d_in[23];
  const float* bv2 =(const float*)d_in[24];
  float* out=(float*)d_out;
  char* ws=(char*)d_ws;
  // layout v4 (peak ~85.7 MB):
  u16*  gpre  =(u16*)ws;                   // [0, 67,108,864)  64 MB, dead after k_scan
  u16*  wcomb =(u16*)(ws+67108864);        // 1,572,864 -> 68,681,728
  float* bcomb=(float*)(ws+68681728);      // 3,072     -> 68,684,800
  u16*  wcat  =(u16*)(ws+68684800);        // 245,760   -> 68,930,560
  float* bcat =(float*)(ws+68930560);      // 3,840     -> 68,934,400
  u16*  shadow=(u16*)(ws+68934400);        // 16,777,216 -> 85,711,616
  u16*  hdn   =(u16*)ws;                   // 25 MB, OVERLAPS dead gpre (k_mem runs after k_scan)

  hipLaunchKernelGGL(k_prep, dim3(192), dim3(256), 0, stream,
                     Ws,bs,bm,Wm,Wh1,bh1,Wt1,bt1,Wv1,bv1,wcat,bcat,bcomb);
  hipLaunchKernelGGL(k_wcomb, dim3(96), dim3(256), 0, stream, Ws,Wm,wcomb);
  hipLaunchKernelGGL(k_route, dim3(1024), dim3(256), 0, stream, hseq,ek,Wi,bi,Wih,bih,bhh,gpre,out);
  hipLaunchKernelGGL(k_scan, dim3(16), dim3(512), 0, stream, Whh,bhh,st0,gpre,shadow);
  hipLaunchKernelGGL(k_expand, dim3(8192), dim3(256), 0, stream, shadow,out+OUT_STATE);
  hipLaunchKernelGGL(k_mem, dim3(512,10), dim3(256), 0, stream, shadow,wcat,bcat,out+OUT_MEM,hdn);
  hipLaunchKernelGGL(k_pool, dim3(64,8), dim3(256), 0, stream, shadow,wcomb,bcomb,out+OUT_POOLED);
  hipLaunchKernelGGL(k_heads, dim3(768), dim3(256), 0, stream, hdn,Wh2,bh2,Wt2,bt2,Wv2,bv2,out);
}

// Round 5
// 859.820 us; speedup vs baseline: 2.1582x; 1.3609x over previous
//
#include <hip/hip_runtime.h>
#include <hip/hip_bf16.h>

typedef unsigned short u16;
typedef unsigned int u32;
typedef __bf16 bf16x8 __attribute__((ext_vector_type(8)));
typedef float f32x4 __attribute__((ext_vector_type(4)));

// output element offsets (f32 elements)
#define OUT_POOLED 0
#define OUT_MEM    6291456
#define OUT_STATE  56623104
#define OUT_HOLD   65011712
#define OUT_ROUTE  65208320

#define SW(r) (((r)&7)<<4)

__device__ __forceinline__ float b2f(u16 u){ u32 v=((u32)u)<<16; float f; __builtin_memcpy(&f,&v,4); return f; }
__device__ __forceinline__ u16 f2b(float f){ __hip_bfloat16 h=__float2bfloat16(f); u16 r; __builtin_memcpy(&r,&h,2); return r; }
__device__ __forceinline__ float sigf(float x){ return __builtin_amdgcn_rcpf(1.0f+__builtin_amdgcn_exp2f(-1.4426950408889634f*x)); }
__device__ __forceinline__ float tanh_(float x){ return 1.0f-2.0f*__builtin_amdgcn_rcpf(1.0f+__builtin_amdgcn_exp2f(2.8853900817779268f*x)); }
__device__ __forceinline__ float geluf(float x){
  float z = 0.7071067811865476f*x;
  float az = __builtin_fabsf(z);
  float t = __builtin_amdgcn_rcpf(1.0f+0.3275911f*az);
  float p = t*(0.254829592f+t*(-0.284496736f+t*(1.421413741f+t*(-1.453152027f+t*1.061405429f))));
  float e = __builtin_amdgcn_exp2f(-1.4426950408889634f*az*az);
  float er = 1.0f-p*e;
  er = (z<0.0f)? -er : er;
  return 0.5f*x*(1.0f+er);
}

// ---------------- prep: wcat pack, bcat, b_comb, + bf16 weight packs (wib2/wihb/wmT) ----------------
__global__ void k_prep(const float* __restrict__ Ws, const float* __restrict__ bs,
                       const float* __restrict__ bm, const float* __restrict__ Wm,
                       const float* __restrict__ Wh1, const float* __restrict__ bh1,
                       const float* __restrict__ Wt1, const float* __restrict__ bt1,
                       const float* __restrict__ Wv1, const float* __restrict__ bv1,
                       const float* __restrict__ Wi, const float* __restrict__ ek,
                       const float* __restrict__ Wih,
                       u16* __restrict__ wcat, float* __restrict__ bcat, float* __restrict__ bcomb,
                       u16* __restrict__ wib2, u16* __restrict__ wihb, u16* __restrict__ wmT)
{
  __shared__ float bmS[768];
  int tid = threadIdx.x;
  for(int i=tid;i<768;i+=256) bmS[i]=bm[i];
  __syncthreads();
  // bcomb: one wave per d
  {
    int w = tid>>6, lane = tid&63;
    int d = blockIdx.x*4 + w;
    float acc=0.f;
    for(int e=0;e<8;e++){
      const float* row = Ws + (size_t)d*6144 + e*768;
      #pragma unroll
      for(int it=0; it<3; it++){
        int c = it*256 + lane*4;
        float4 u = *reinterpret_cast<const float4*>(row + c);
        acc += u.x*bmS[c]+u.y*bmS[c+1]+u.z*bmS[c+2]+u.w*bmS[c+3];
      }
    }
    #pragma unroll
    for(int o=32;o>0;o>>=1) acc += __shfl_down(acc,o);
    if(lane==0) bcomb[d]=bs[d]+acc;
  }
  // bcat(960) + wcat(122880) + wib2(110592) + wihb(49152) + wmT(98304) = 381888
  for(int idx = blockIdx.x*256+tid; idx<381888; idx += gridDim.x*256){
    if(idx<960){
      int n=idx;
      float v;
      if(n<768) v=bm[n];
      else { int j=n-768; v = (j<64)? bh1[j] : (j<128)? bt1[j-64] : bv1[j-128]; }
      bcat[n]=v;
    } else if(idx<123840){
      int c=idx-960; int n=c>>7, k=c&127;
      float v;
      if(n<768) v=Wm[n*128+k];
      else if(n<832) v=Wh1[(n-768)*128+k];
      else if(n<896) v=Wt1[(n-832)*128+k];
      else v=Wv1[(n-896)*128+k];
      wcat[c]=f2b(v);
    } else if(idx<234432){
      int j=idx-123840; int r=j/768, k=j-r*768;
      float v = (r<128)? Wi[r*768+k] : (r<136)? ek[(r-128)*768+k] : 0.f;
      wib2[j]=f2b(v);
    } else if(idx<283584){
      int j=idx-234432;
      wihb[j]=f2b(Wih[j]);
    } else {
      int j=idx-283584; int s=j/768, d2=j-s*768;
      wmT[j]=f2b(Wm[d2*128+s]);
    }
  }
}

// ---------------- Wcomb via MFMA: C[d][e*128+s] = sum_d2 Ws[d][e*768+d2]*Wm[d2][s] ----------------
// 96-k tiles use ODD-STRIDE padding (208B rows, 52 dwords = 20 mod 32 -> max 2-way bank
// conflict) instead of XOR swizzle: (r&7) XOR over 12 slots/row overflows the row (R4 bug).
__global__ __launch_bounds__(256,2) void k_wcomb(const float* __restrict__ Ws, const u16* __restrict__ wmT,
                                                 u16* __restrict__ wcomb)
{
  __shared__ u16 AsU[128*104];
  __shared__ u16 BsU[128*104];
  char* AsB=(char*)AsU; char* BsB=(char*)BsU;
  int tid=threadIdx.x;
  int dt=blockIdx.x, e=blockIdx.y;
  int d0=dt*128;
  int w=tid>>6, L=tid&63, q4=L>>4, il=L&15;
  int msub=w*32;
  const f32x4 fz={0.f,0.f,0.f,0.f};
  f32x4 acc[2][8];
  #pragma unroll
  for(int tm=0;tm<2;tm++)
    #pragma unroll
    for(int tn=0;tn<8;tn++) acc[tm][tn]=fz;
  for(int kc=0;kc<8;kc++){
    __syncthreads();
    // As: 128 d-rows x 96 k, f32->bf16 (full: 3072 uint2 slots)
    for(int it=0;it<12;it++){
      int slot=it*256+tid; int r=slot/24, c4=(slot-r*24)*4;
      float4 u=*reinterpret_cast<const float4*>(Ws + (size_t)(d0+r)*6144 + e*768 + kc*96 + c4);
      u16 v[4]={f2b(u.x),f2b(u.y),f2b(u.z),f2b(u.w)};
      uint2 p; __builtin_memcpy(&p,v,8);
      *reinterpret_cast<uint2*>(AsB + r*208 + c4*2) = p;
    }
    // Bs: 128 s-rows x 96 k from wmT (full: 1536 uint4 slots)
    for(int it=0;it<6;it++){
      int slot=it*256+tid; int r=slot/12, o8=(slot-r*12)*8;
      uint4 u=*reinterpret_cast<const uint4*>(wmT + (size_t)r*768 + kc*96 + o8);
      *reinterpret_cast<uint4*>(BsB + r*208 + o8*2) = u;
    }
    __syncthreads();
    #pragma unroll
    for(int kt=0;kt<3;kt++){
      int kb=(kt*32+q4*8)*2;
      bf16x8 a0=__builtin_bit_cast(bf16x8,*reinterpret_cast<const uint4*>(AsB + (msub+il)*208 + kb));
      bf16x8 a1=__builtin_bit_cast(bf16x8,*reinterpret_cast<const uint4*>(AsB + (msub+16+il)*208 + kb));
      #pragma unroll
      for(int tn=0;tn<8;tn++){
        bf16x8 b=__builtin_bit_cast(bf16x8,*reinterpret_cast<const uint4*>(BsB + (tn*16+il)*208 + kb));
        acc[0][tn]=__builtin_amdgcn_mfma_f32_16x16x32_bf16(a0,b,acc[0][tn],0,0,0);
        acc[1][tn]=__builtin_amdgcn_mfma_f32_16x16x32_bf16(a1,b,acc[1][tn],0,0,0);
      }
    }
  }
  #pragma unroll
  for(int tm=0;tm<2;tm++){
    #pragma unroll
    for(int tn=0;tn<8;tn++){
      #pragma unroll
      for(int i=0;i<4;i++){
        int d=d0+msub+tm*16+q4*4+i;
        wcomb[d*1024 + e*128 + tn*16+il]=f2b(acc[tm][tn][i]);
      }
    }
  }
}

// ---------------- route v5b: MFMA GEMMs (proj+logits fused, q) + softmax + gpre emit ----------------
// A-tile 16 rows hseq (bf16, XOR swizzle, 1536B rows: in-bounds). proj B = wib2 [144][768]
// staged FULL per 96-k chunk at 208B row stride (no swizzle). q B = wihb [384][128] staged
// FULL per 32-k chunk at 80B row stride. q kept f32 in LDS (aliases dead A-tile).
__global__ __launch_bounds__(256,2) void k_route(const float* __restrict__ hseq,
                                                 const u16* __restrict__ wib2, const u16* __restrict__ wihb,
                                                 const float* __restrict__ bi,
                                                 const float* __restrict__ bih, const float* __restrict__ bhh,
                                                 u16* __restrict__ gpre, float* __restrict__ out)
{
  __shared__ u16 AsU[16*768];     // 24,576 B; after q-phase aliased as qS f32[16][384]
  __shared__ u16 BsU[15360];      // 30,720 B: proj B 144x104u16; q B 384x40u16
  __shared__ u16 prS[16*128];     // proj bf16, swizzled (256B rows: in-bounds)
  __shared__ float lgs[16][8];
  __shared__ float wSm[16][8];
  __shared__ float biS[128];
  __shared__ float bS[384];
  char* AsB=(char*)AsU; char* BsB=(char*)BsU; char* prB=(char*)prS;
  int tid=threadIdx.x;
  int row0=blockIdx.x*16;
  // stage A (16x768)
  {
    int r=tid>>4, c0=(tid&15)*48;
    const float* src=hseq+(size_t)(row0+r)*768+c0;
    #pragma unroll
    for(int m=0;m<12;m++){
      float4 u=*reinterpret_cast<const float4*>(src+m*4);
      u16 v[4]={f2b(u.x),f2b(u.y),f2b(u.z),f2b(u.w)};
      uint2 p; __builtin_memcpy(&p,v,8);
      int k=c0+m*4;
      *reinterpret_cast<uint2*>(AsB + r*1536 + ((k*2)^SW(r))) = p;
    }
  }
  if(tid<32){ *reinterpret_cast<float4*>(&biS[tid*4]) = *reinterpret_cast<const float4*>(bi+tid*4); }
  if(tid>=64&&tid<160){
    int j4=(tid-64)*4;
    float4 u=*reinterpret_cast<const float4*>(bih+j4);
    if(j4<256){ float4 v=*reinterpret_cast<const float4*>(bhh+j4); u.x+=v.x;u.y+=v.y;u.z+=v.z;u.w+=v.w; }
    *reinterpret_cast<float4*>(&bS[j4])=u;
  }
  int w=tid>>6, L=tid&63, q4=L>>4, il=L&15;
  // proj: 9 n-tiles: wave w owns tn = w, w+4, w+8 (<9)
  int ntP=(w==0)?3:2;
  f32x4 accP[3];
  #pragma unroll
  for(int i=0;i<3;i++) accP[i]=(f32x4){0.f,0.f,0.f,0.f};
  for(int kc=0;kc<8;kc++){
    __syncthreads();
    // FULL staging: 144 rows x 12 uint4 = 1728 slots
    for(int it=0;it<7;it++){
      int slot=it*256+tid;
      if(slot<1728){
        int r=slot/12, o8=(slot-r*12)*8;
        uint4 u=*reinterpret_cast<const uint4*>(wib2 + (size_t)r*768 + kc*96 + o8);
        *reinterpret_cast<uint4*>(BsB + r*208 + o8*2) = u;
      }
    }
    __syncthreads();
    #pragma unroll
    for(int kt=0;kt<3;kt++){
      int k=kc*96+kt*32+q4*8;
      bf16x8 a=__builtin_bit_cast(bf16x8,*reinterpret_cast<const uint4*>(AsB + il*1536 + ((k*2)^SW(il))));
      int kb=(kt*32+q4*8)*2;
      #pragma unroll
      for(int t3=0;t3<3;t3++){
        if(t3<ntP){
          int col=(w+t3*4)*16+il;
          bf16x8 b=__builtin_bit_cast(bf16x8,*reinterpret_cast<const uint4*>(BsB + col*208 + kb));
          accP[t3]=__builtin_amdgcn_mfma_f32_16x16x32_bf16(a,b,accP[t3],0,0,0);
        }
      }
    }
  }
  // proj epilogue: cols<128 -> prS bf16 (+bi); tile 8 cols 128-135 -> lgs
  #pragma unroll
  for(int t3=0;t3<3;t3++){
    if(t3<ntP){
      int tn=w+t3*4;
      #pragma unroll
      for(int i=0;i<4;i++){
        int r=q4*4+i;
        float v=accP[t3][i];
        if(tn<8){
          int col=tn*16+il;
          *reinterpret_cast<u16*>(prB + r*256 + ((col*2)^SW(r))) = f2b(v+biS[col]);
        } else if(il<8){
          lgs[r][il]=v*(1.0f/27.712812921102035f);
        }
      }
    }
  }
  __syncthreads();
  if(tid<16){
    int r=tid;
    float l[8],m=-1e30f;
    #pragma unroll
    for(int e=0;e<8;e++){ l[e]=lgs[r][e]; m=fmaxf(m,l[e]); }
    float s=0.f;
    #pragma unroll
    for(int e=0;e<8;e++){ l[e]=__builtin_amdgcn_exp2f(1.4426950408889634f*(l[e]-m)); s+=l[e]; }
    float inv=__builtin_amdgcn_rcpf(s);
    #pragma unroll
    for(int e=0;e<8;e++){ float wv=l[e]*inv; wSm[r][e]=wv; out[OUT_ROUTE+(row0+r)*8+e]=wv; }
  }
  // q GEMM: 24 n-tiles, wave w owns tn = w + 4*t6
  f32x4 accQ[6];
  #pragma unroll
  for(int i=0;i<6;i++) accQ[i]=(f32x4){0.f,0.f,0.f,0.f};
  for(int kt=0;kt<4;kt++){
    __syncthreads();
    // FULL staging: 384 rows x 4 uint4 (32 k each) = 1536 slots
    for(int it=0;it<6;it++){
      int slot=it*256+tid;
      int r=slot>>2, qt=slot&3;
      uint4 u=*reinterpret_cast<const uint4*>(wihb + (size_t)r*128 + kt*32 + qt*8);
      *reinterpret_cast<uint4*>(BsB + r*80 + qt*16) = u;
    }
    __syncthreads();
    int kb=(kt*32+q4*8)*2;
    bf16x8 a=__builtin_bit_cast(bf16x8,*reinterpret_cast<const uint4*>(prB + il*256 + (kb^SW(il))));
    #pragma unroll
    for(int t6=0;t6<6;t6++){
      int col=(w+t6*4)*16+il;
      bf16x8 b=__builtin_bit_cast(bf16x8,*reinterpret_cast<const uint4*>(BsB + col*80 + q4*16));
      accQ[t6]=__builtin_amdgcn_mfma_f32_16x16x32_bf16(a,b,accQ[t6],0,0,0);
    }
  }
  // qS f32 (aliases AsU; A-tile dead)
  float* qS=(float*)AsU;
  #pragma unroll
  for(int t6=0;t6<6;t6++){
    int col=(w+t6*4)*16+il;
    #pragma unroll
    for(int i=0;i<4;i++) qS[(q4*4+i)*384+col]=accQ[t6][i];
  }
  __syncthreads();
  // gpre emit: ch = tid&127, half = tid>>7
  {
    int ch=tid&127, hh=tid>>7;
    float b0=bS[ch], b1=bS[128+ch], b2=bS[256+ch];
    #pragma unroll 1
    for(int r=0;r<16;r++){
      float q0=qS[r*384+ch], q1=qS[r*384+128+ch], q2=qS[r*384+256+ch];
      u16* dst=gpre+(size_t)(row0+r)*4096;
      #pragma unroll
      for(int j=0;j<4;j++){
        int e=(hh+j*2)&7;
        float wv=wSm[r][e];
        u16 ov[4]={f2b(wv*q0+b0),f2b(wv*q1+b1),f2b(wv*q2+b2),0};
        uint2 o; __builtin_memcpy(&o,ov,8);
        *reinterpret_cast<uint2*>(dst + (e*128+ch)*4)=o;
      }
    }
  }
}

// ---------------- sequential GRU scan (unchanged v3) ----------------
#define SCAN_SYNC asm volatile("s_waitcnt lgkmcnt(0)\n\ts_barrier" ::: "memory")

#define SCAN_STEP(BUF,NXT,P,DOLOAD)                                                         \
  {                                                                                         \
    bf16x8 af[4];                                                                           \
    _Pragma("unroll")                                                                       \
    for(int kt=0;kt<4;kt++)                                                                 \
      af[kt]=__builtin_bit_cast(bf16x8, *reinterpret_cast<const uint4*>(&hbf[BUF][il>>2][kt*32+q4*8])); \
    u16 cw[4];                                                                              \
    __builtin_memcpy(cw,&gv[P],8);                                                          \
    if(DOLOAD){                                                                             \
      gv[P]=*reinterpret_cast<const uint2*>(gp);                                            \
      gp+=4096;                                                                             \
    }                                                                                       \
    f32x4 acc0={0.f,0.f,0.f,0.f}, acc1={0.f,0.f,0.f,0.f}, acc2={0.f,0.f,0.f,0.f};           \
    _Pragma("unroll")                                                                       \
    for(int kt=0;kt<4;kt++){                                                                \
      acc0=__builtin_amdgcn_mfma_f32_16x16x32_bf16(af[kt],bfr0[kt],acc0,0,0,0);             \
      acc1=__builtin_amdgcn_mfma_f32_16x16x32_bf16(af[kt],bfr1[kt],acc1,0,0,0);             \
      acc2=__builtin_amdgcn_mfma_f32_16x16x32_bf16(af[kt],bfr2[kt],acc2,0,0,0);             \
    }                                                                                       \
    {                                                                                       \
      float r=sigf(acc0[0]+b2f(cw[0]));                                                     \
      float z=sigf(acc1[0]+b2f(cw[1]));                                                     \
      float n=tanh_(b2f(cw[2])+r*(acc2[0]+bhhn));                                           \
      float hn=n+z*(hp-n);                                                                  \
      hp=hn;                                                                                \
      u16 hb=f2b(hn);                                                                       \
      hbf[NXT][q4][ch]=hb;                                                                  \
      *sbase=hb;                                                                            \
    }                                                                                       \
    sbase += 1024;                                                                          \
    SCAN_SYNC;                                                                              \
  }

__global__ __launch_bounds__(512,1) void k_scan(const float* __restrict__ Whh, const float* __restrict__ bhh,
                                                const float* __restrict__ state0,
                                                const u16* __restrict__ gpre, u16* __restrict__ shadow)
{
  __shared__ u16 hbf[2][4][144];
  int tid=threadIdx.x;
  int w=tid>>6, L=tid&63, q4=L>>4, il=L&15;
  int blk=blockIdx.x;
  int b=blk>>1, e0=(blk&1)*4;
  int ch=w*16+il;
  bf16x8 bfr0[4], bfr1[4], bfr2[4];
  #pragma unroll
  for(int kt=0; kt<4; kt++){
    u16 t0[8],t1[8],t2[8];
    #pragma unroll
    for(int j=0;j<8;j++){
      t0[j]=f2b(Whh[(0*128+ch)*128 + kt*32 + q4*8 + j]);
      t1[j]=f2b(Whh[(1*128+ch)*128 + kt*32 + q4*8 + j]);
      t2[j]=f2b(Whh[(2*128+ch)*128 + kt*32 + q4*8 + j]);
    }
    __builtin_memcpy(&bfr0[kt],t0,16);
    __builtin_memcpy(&bfr1[kt],t1,16);
    __builtin_memcpy(&bfr2[kt],t2,16);
  }
  float bhhn = bhh[256+ch];
  float hp = state0[(e0+q4)*128+ch];
  {
    int cc=tid>>7, chh=tid&127;
    hbf[0][cc][chh]=f2b(state0[(e0+cc)*128+chh]);
  }
  const u16* gp = gpre + (size_t)b*1024*4096 + ((e0+q4)*128+ch)*4;
  u16* sbase = shadow + ((size_t)b*1024*8 + (e0+q4))*128 + ch;
  uint2 gv[4];
  #pragma unroll
  for(int p=0;p<4;p++){
    gv[p]=*reinterpret_cast<const uint2*>(gp);
    gp+=4096;
  }
  SCAN_SYNC;
  #pragma unroll 1
  for(int t2=0;t2<255;t2++){
    SCAN_STEP(0,1,0,1)
    SCAN_STEP(1,0,1,1)
    SCAN_STEP(0,1,2,1)
    SCAN_STEP(1,0,3,1)
  }
  SCAN_STEP(0,1,0,0)
  SCAN_STEP(1,0,1,0)
  SCAN_STEP(0,1,2,0)
  SCAN_STEP(1,0,3,0)
}

// ---------------- expand bf16 shadow -> f32 OUT_STATE ----------------
__global__ __launch_bounds__(256) void k_expand(const u16* __restrict__ sh, float* __restrict__ o)
{
  int idx=(blockIdx.x*256+threadIdx.x)*4;
  uint2 u=*reinterpret_cast<const uint2*>(sh+idx);
  float4 f;
  f.x=b2f((u16)(u.x&0xffffu)); f.y=b2f((u16)(u.x>>16));
  f.z=b2f((u16)(u.y&0xffffu)); f.w=b2f((u16)(u.y>>16));
  *reinterpret_cast<float4*>(o+idx)=f;
}

// ---------------- memory_stack + head hidden (GEMM [65536x128]@[128x960]) ----------------
__global__ __launch_bounds__(256) void k_mem(const u16* __restrict__ state, const u16* __restrict__ wcat,
                                             const float* __restrict__ bcat,
                                             float* __restrict__ memout, u16* __restrict__ hdn)
{
  __shared__ u16 As[128][136];
  __shared__ u16 Bs[96][136];
  int tid=threadIdx.x;
  int bx=blockIdx.x, ny=blockIdx.y;
  for(int it=0;it<8;it++){
    int v=it*256+tid; int r=v>>4, c8=(v&15)*8;
    *reinterpret_cast<uint4*>(&As[r][c8]) = *reinterpret_cast<const uint4*>(state + (bx*128+r)*128 + c8);
  }
  for(int it=0;it<6;it++){
    int v=it*256+tid; int r=v>>4, c8=(v&15)*8;
    *reinterpret_cast<uint4*>(&Bs[r][c8]) = *reinterpret_cast<const uint4*>(wcat + (ny*96+r)*128 + c8);
  }
  __syncthreads();
  int w=tid>>6, L=tid&63, q4=L>>4, il=L&15;
  int msub=w*32;
  bf16x8 af[2][4];
  #pragma unroll
  for(int tm=0;tm<2;tm++)
    #pragma unroll
    for(int kt=0;kt<4;kt++)
      af[tm][kt]=__builtin_bit_cast(bf16x8,*reinterpret_cast<const uint4*>(&As[msub+tm*16+il][kt*32+q4*8]));
  const f32x4 fz = {0.f,0.f,0.f,0.f};
  f32x4 acc[2][6];
  #pragma unroll
  for(int tm=0;tm<2;tm++){
    #pragma unroll
    for(int tn=0;tn<6;tn++) acc[tm][tn]=fz;
  }
  #pragma unroll
  for(int tn=0;tn<6;tn++){
    bf16x8 bf[4];
    #pragma unroll
    for(int kt=0;kt<4;kt++)
      bf[kt]=__builtin_bit_cast(bf16x8,*reinterpret_cast<const uint4*>(&Bs[tn*16+il][kt*32+q4*8]));
    #pragma unroll
    for(int tm=0;tm<2;tm++){
      #pragma unroll
      for(int kt=0;kt<4;kt++)
        acc[tm][tn]=__builtin_amdgcn_mfma_f32_16x16x32_bf16(af[tm][kt],bf[kt],acc[tm][tn],0,0,0);
    }
  }
  #pragma unroll
  for(int tm=0;tm<2;tm++){
    #pragma unroll
    for(int tn=0;tn<6;tn++){
      int col=ny*96+tn*16+il;
      float bias=bcat[col];
      #pragma unroll
      for(int i=0;i<4;i++){
        int row=bx*128+msub+tm*16+q4*4+i;
        float val=acc[tm][tn][i]+bias;
        if(ny<8) memout[row*768+col]=val;
        else hdn[row*192+(col-768)]=f2b(geluf(val));
      }
    }
  }
}

// ---------------- pooled = state_flat[8192x1024] @ Wcomb.T + b_comb ----------------
__global__ __launch_bounds__(256) void k_pool(const u16* __restrict__ state, const u16* __restrict__ wcomb,
                                              const float* __restrict__ bcomb, float* __restrict__ pooled)
{
  __shared__ u16 As[128][136];
  __shared__ u16 Bs[96][136];
  int tid=threadIdx.x;
  int bx=blockIdx.x, ny=blockIdx.y;
  int w=tid>>6, L=tid&63, q4=L>>4, il=L&15;
  int msub=w*32;
  const f32x4 fz = {0.f,0.f,0.f,0.f};
  f32x4 acc[2][6];
  #pragma unroll
  for(int tm=0;tm<2;tm++){
    #pragma unroll
    for(int tn=0;tn<6;tn++) acc[tm][tn]=fz;
  }
  for(int kc=0;kc<8;kc++){
    __syncthreads();
    for(int it=0;it<8;it++){
      int v=it*256+tid; int r=v>>4, c8=(v&15)*8;
      *reinterpret_cast<uint4*>(&As[r][c8]) = *reinterpret_cast<const uint4*>(state + (bx*128+r)*1024 + kc*128 + c8);
    }
    for(int it=0;it<6;it++){
      int v=it*256+tid; int r=v>>4, c8=(v&15)*8;
      *reinterpret_cast<uint4*>(&Bs[r][c8]) = *reinterpret_cast<const uint4*>(wcomb + (ny*96+r)*1024 + kc*128 + c8);
    }
    __syncthreads();
    bf16x8 af[2][4];
    #pragma unroll
    for(int tm=0;tm<2;tm++)
      #pragma unroll
      for(int kt=0;kt<4;kt++)
        af[tm][kt]=__builtin_bit_cast(bf16x8,*reinterpret_cast<const uint4*>(&As[msub+tm*16+il][kt*32+q4*8]));
    #pragma unroll
    for(int tn=0;tn<6;tn++){
      bf16x8 bf[4];
      #pragma unroll
      for(int kt=0;kt<4;kt++)
        bf[kt]=__builtin_bit_cast(bf16x8,*reinterpret_cast<const uint4*>(&Bs[tn*16+il][kt*32+q4*8]));
      #pragma unroll
      for(int tm=0;tm<2;tm++){
        #pragma unroll
        for(int kt=0;kt<4;kt++)
          acc[tm][tn]=__builtin_amdgcn_mfma_f32_16x16x32_bf16(af[tm][kt],bf[kt],acc[tm][tn],0,0,0);
      }
    }
  }
  #pragma unroll
  for(int tm=0;tm<2;tm++){
    #pragma unroll
    for(int tn=0;tn<6;tn++){
      int col=ny*96+tn*16+il;
      float bias=bcomb[col];
      #pragma unroll
      for(int i=0;i<4;i++){
        int row=bx*128+msub+tm*16+q4*4+i;
        pooled[row*768+col]=acc[tm][tn][i]+bias;
      }
    }
  }
}

// ---------------- head second layer ----------------
__global__ __launch_bounds__(256) void k_heads(const u16* __restrict__ hdn,
                                               const float* __restrict__ Wh2, const float* __restrict__ bh2,
                                               const float* __restrict__ Wt2, const float* __restrict__ bt2,
                                               const float* __restrict__ Wv2, const float* __restrict__ bv2,
                                               float* __restrict__ out)
{
  int oid=blockIdx.x*256+threadIdx.x;
  int row=oid&65535, head=oid>>16;
  const float* w2 = (head==0)?Wh2:(head==1)?Wt2:Wv2;
  float b2 = ((head==0)?bh2:(head==1)?bt2:bv2)[0];
  float acc=0.f;
  const u16* src = hdn + row*192 + head*64;
  for(int j0=0;j0<64;j0+=8){
    uint4 hu=*reinterpret_cast<const uint4*>(src+j0);
    u16 hs[8]; __builtin_memcpy(hs,&hu,16);
    #pragma unroll
    for(int j=0;j<8;j++) acc+=b2f(hs[j])*w2[j0+j];
  }
  out[OUT_HOLD + head*65536 + row]=acc+b2;
}

extern "C" void kernel_launch(void* const* d_in, const int* in_sizes, int n_in,
                              void* d_out, int out_size, void* d_ws, size_t ws_size,
                              hipStream_t stream)
{
  const float* hseq=(const float*)d_in[0];
  const float* ek  =(const float*)d_in[1];
  const float* st0 =(const float*)d_in[2];
  const float* Wi  =(const float*)d_in[3];
  const float* bi  =(const float*)d_in[4];
  const float* Wih =(const float*)d_in[5];
  const float* Whh =(const float*)d_in[6];
  const float* bih =(const float*)d_in[7];
  const float* bhh =(const float*)d_in[8];
  const float* Wm  =(const float*)d_in[9];
  const float* bm  =(const float*)d_in[10];
  const float* Ws  =(const float*)d_in[11];
  const float* bs  =(const float*)d_in[12];
  const float* Wh1 =(const float*)d_in[13];
  const float* bh1 =(const float*)d_in[14];
  const float* Wh2 =(const float*)d_in[15];
  const float* bh2 =(const float*)d_in[16];
  const float* Wt1 =(const float*)d_in[17];
  const float* bt1 =(const float*)d_in[18];
  const float* Wt2 =(const float*)d_in[19];
  const float* bt2 =(const float*)d_in[20];
  const float* Wv1 =(const float*)d_in[21];
  const float* bv1 =(const float*)d_in[22];
  const float* Wv2 =(const float*)d_in[23];
  const float* bv2 =(const float*)d_in[24];
  float* out=(float*)d_out;
  char* ws=(char*)d_ws;
  // layout v5 (peak ~86.3 MB):
  u16*  gpre  =(u16*)ws;                   // [0, 67,108,864)  64 MB, dead after k_scan
  u16*  wcomb =(u16*)(ws+67108864);        // 1,572,864 -> 68,681,728
  float* bcomb=(float*)(ws+68681728);      // 3,072     -> 68,684,800
  u16*  wcat  =(u16*)(ws+68684800);        // 245,760   -> 68,930,560
  float* bcat =(float*)(ws+68930560);      // 3,840     -> 68,934,400
  u16*  shadow=(u16*)(ws+68934400);        // 16,777,216 -> 85,711,616
  u16*  wib2  =(u16*)(ws+85711616);        // 221,184   -> 85,932,800
  u16*  wihb  =(u16*)(ws+85932800);        // 98,304    -> 86,031,104
  u16*  wmT   =(u16*)(ws+86031104);        // 196,608   -> 86,227,712
  u16*  hdn   =(u16*)ws;                   // 25 MB, OVERLAPS dead gpre (k_mem runs after k_scan)

  hipLaunchKernelGGL(k_prep, dim3(192), dim3(256), 0, stream,
                     Ws,bs,bm,Wm,Wh1,bh1,Wt1,bt1,Wv1,bv1,Wi,ek,Wih,wcat,bcat,bcomb,wib2,wihb,wmT);
  hipLaunchKernelGGL(k_wcomb, dim3(6,8), dim3(256), 0, stream, Ws,wmT,wcomb);
  hipLaunchKernelGGL(k_route, dim3(512), dim3(256), 0, stream, hseq,wib2,wihb,bi,bih,bhh,gpre,out);
  hipLaunchKernelGGL(k_scan, dim3(16), dim3(512), 0, stream, Whh,bhh,st0,gpre,shadow);
  hipLaunchKernelGGL(k_expand, dim3(8192), dim3(256), 0, stream, shadow,out+OUT_STATE);
  hipLaunchKernelGGL(k_mem, dim3(512,10), dim3(256), 0, stream, shadow,wcat,bcat,out+OUT_MEM,hdn);
  hipLaunchKernelGGL(k_pool, dim3(64,8), dim3(256), 0, stream, shadow,wcomb,bcomb,out+OUT_POOLED);
  hipLaunchKernelGGL(k_heads, dim3(768), dim3(256), 0, stream, hdn,Wh2,bh2,Wt2,bt2,Wv2,bv2,out);
}